// Round 17
// baseline (148.392 us; speedup 1.0000x reference)
//
#include <hip/hip_runtime.h>
#include <hip/hip_bf16.h>

// Problem constants
#define NB 8
#define LL 1024        // H*W tokens per batch
#define CIN 512
#define DIN 1024       // d_inner
#define DXBC 1152      // d_inner + 2*d_state
#define DPROJ 2192     // actual in_proj rows
#define NPADW 2304     // ZX row stride (padded)
#define NUSE 2176      // cols of ZX actually consumed (z + xBC); 34 x 64
#define NHH 16
#define HDD 64
#define DST 64
#define NCHUNK 16
#define QCH 64         // chunk length
#define XBCS 1024      // XBC stored stride (x-part only)
#define CTT 4          // conv tokens per 144-lane group (block covers 2*CTT = 8 tokens)
#define DTB 16         // dt tokens per block

typedef unsigned short u16;
typedef unsigned int u32;
typedef __bf16 bf16x8 __attribute__((ext_vector_type(8)));
typedef float f32x4 __attribute__((ext_vector_type(4)));
typedef u16 u16x8 __attribute__((ext_vector_type(8)));

__device__ __forceinline__ float bf2f(u16 u) {
    u32 x = ((u32)u) << 16; float f; __builtin_memcpy(&f, &x, 4); return f;
}
__device__ __forceinline__ u16 f2bf(float f) {
    u32 x; __builtin_memcpy(&x, &f, 4);
    u32 r = x + 0x7fff + ((x >> 16) & 1);
    return (u16)(r >> 16);
}

__device__ __forceinline__ void gload16(const u16* g, u16* l) {
    __builtin_amdgcn_global_load_lds((__attribute__((address_space(1))) void*)(g),
                                     (__attribute__((address_space(3))) void*)(l), 16, 0, 0);
}

// swizzled u16 index into a [64][64] bf16 LDS tile (128B rows, 16B-slot XOR swizzle)
__device__ __forceinline__ int swz(int row, int cb) {
    return row * 64 + ((cb ^ ((row & 7) << 4)) >> 1);
}

// ---------- fused weight prep: Win pad-convert | Wc2 convert | BN prep ----------
#define PREP_WIN_BLKS 4608   // NPADW*CIN/256
#define PREP_WC2_BLKS 1024   // CIN*CIN/256
__global__ __launch_bounds__(256) void prep_all(const float* __restrict__ ipw, u16* __restrict__ Win,
                                                const float* __restrict__ c2w, u16* __restrict__ Wc2,
                                                const float* __restrict__ cb, const float* __restrict__ g,
                                                const float* __restrict__ bb, const float* __restrict__ mean,
                                                const float* __restrict__ var,
                                                float* __restrict__ scale, float* __restrict__ shift) {
    int bid = blockIdx.x;
    if (bid < PREP_WIN_BLKS) {
        int i = bid * 256 + threadIdx.x;
        Win[i] = (i < DPROJ * CIN) ? f2bf(ipw[i]) : (u16)0;
    } else if (bid < PREP_WIN_BLKS + PREP_WC2_BLKS) {
        int i = (bid - PREP_WIN_BLKS) * 256 + threadIdx.x;
        Wc2[i] = f2bf(c2w[i]);
    } else {
        int i = (bid - PREP_WIN_BLKS - PREP_WC2_BLKS) * 256 + threadIdx.x;
        if (i < CIN) {
            float rs = rsqrtf(var[i] + 1e-5f);
            float sc = g[i] * rs;
            scale[i] = sc;
            shift[i] = (cb[i] - mean[i]) * sc + bb[i];
        }
    }
}

// WoutT[d][c] = out_proj_w[c][d] * rms_w[d]   (LDS-tiled transpose, 64x64 tiles)
__global__ __launch_bounds__(256) void woutT_conv(const float* __restrict__ s,
                                                  const float* __restrict__ rw,
                                                  u16* __restrict__ dt) {
    __shared__ float tile[64][65];
    int bc = blockIdx.x & 7, bd = blockIdx.x >> 3;
    int c0 = bc * 64, d0 = bd * 64;
    int t = threadIdx.x;
    int r4 = t >> 6, cc = t & 63;
#pragma unroll
    for (int rr = 0; rr < 16; ++rr) {
        int row = r4 * 16 + rr;
        tile[row][cc] = s[(size_t)(c0 + row) * DIN + d0 + cc];
    }
    __syncthreads();
#pragma unroll
    for (int rr = 0; rr < 16; ++rr) {
        int row = r4 * 16 + rr;
        dt[(size_t)(d0 + row) * CIN + c0 + cc] = f2bf(tile[cc][row] * rw[d0 + row]);
    }
}

// ---------- LayerNorm over channels + transpose (B,C,HW) -> (tok, C) bf16 ----------
__global__ __launch_bounds__(256) void ln_kernel(const float* __restrict__ x,
                                                 const float* __restrict__ lw,
                                                 const float* __restrict__ lb,
                                                 u16* __restrict__ xn) {
    __shared__ u16 tile[CIN * 33];
    __shared__ float psum[8][32], psq[8][32], muA[32], rsA[32];
    int bid = blockIdx.x;
    int b = bid >> 5, hw0 = (bid & 31) * 32;
    int t = threadIdx.x;
    int hw = t & 31, cg = t >> 5;
    const float* xb = x + (size_t)b * CIN * LL + hw0 + hw;
    float s = 0.f, sq = 0.f;
    for (int r = 0; r < CIN / 8; ++r) {
        int c = r * 8 + cg;
        float v = xb[(size_t)c * LL];
        s += v; sq += v * v;
        tile[c * 33 + hw] = f2bf(v);
    }
    psum[cg][hw] = s; psq[cg][hw] = sq;
    __syncthreads();
    if (t < 32) {
        float ss = 0.f, qq = 0.f;
        for (int g = 0; g < 8; ++g) { ss += psum[g][t]; qq += psq[g][t]; }
        float mu = ss * (1.f / CIN);
        float var = qq * (1.f / CIN) - mu * mu;
        muA[t] = mu; rsA[t] = rsqrtf(var + 1e-5f);
    }
    __syncthreads();
    for (int r = 0; r < 64; ++r) {
        int idx = r * 256 + t;
        int c = idx & (CIN - 1);
        int hh = idx >> 9;
        float v = (bf2f(tile[c * 33 + hh]) - muA[hh]) * rsA[hh] * lw[c] + lb[c];
        xn[((size_t)(b * LL + hw0 + hh)) * CIN + c] = f2bf(v);
    }
}

// ---------- bf16 MFMA GEMM: 128x64 tile, BK=64, XOR-swizzled LDS, 2-phase counted vmcnt ----------
// EPI 0: bf16 store row-major ldc.
// EPI 1: v*rs(col from PS) -> BN(scale/shift[row]) -> ReLU -> remapped f32 store (d_out layout).
template <int EPI>
__global__ __launch_bounds__(256) void gemm_bt(const u16* __restrict__ A, const u16* __restrict__ Bw,
                                               void* __restrict__ Cout, int M, int N, int K, int ldc,
                                               int nx,
                                               const float* __restrict__ scale,
                                               const float* __restrict__ shift,
                                               const float* __restrict__ PS) {
    __shared__ u16 As[2][128 * 64], Bs[2][64 * 64];
    __shared__ float rsl[64];
    int t = threadIdx.x;
    int lane = t & 63, wave = t >> 6;
    // bijective XCD swizzle (m204)
    int nblk = gridDim.x;
    int qq = nblk >> 3, rm = nblk & 7;
    int xcd = blockIdx.x & 7, idx = blockIdx.x >> 3;
    int swzb = (xcd < rm ? xcd * (qq + 1) : rm * (qq + 1) + (xcd - rm) * qq) + idx;
    int m0 = (swzb / nx) * 128, n0 = (swzb % nx) * 64;
    int wr = wave >> 1, wc = wave & 1;
    f32x4 acc[4][2];
    for (int m = 0; m < 4; ++m)
        for (int n = 0; n < 2; ++n)
            for (int q = 0; q < 4; ++q) acc[m][n][q] = 0.f;

    if (EPI == 1) {
        if (t < 64) {
            int tok = n0 + t;
            int b = tok >> 10, rem = tok & 1023;
            int c = rem >> 6, ii = rem & 63;
            float s = 0.f;
#pragma unroll
            for (int h = 0; h < NHH; ++h)
                s += PS[(size_t)(((b << 4) + h) * 16 + c) * 64 + ii];
            rsl[t] = rsqrtf(s * (1.f / DIN) + 1e-5f);
        }
        __syncthreads();
    }

    const u16* Arow = A + (size_t)m0 * K;
    const u16* Brow = Bw + (size_t)n0 * K;
    int s4 = lane >> 4;
    int rr = lane & 15;

    auto STAGE = [&](int buf, int k0) {
#pragma unroll
        for (int j = 0; j < 4; ++j) {
            int e = j * 256 + t;          // A: 1024 16B-slots, 8 per row
            int r = e >> 3, sr = e & 7;
            int src = (sr ^ (r & 7)) * 8;
            gload16(Arow + (size_t)r * K + k0 + src, &As[buf][e * 8]);
        }
#pragma unroll
        for (int j = 0; j < 2; ++j) {
            int e = j * 256 + t;          // B: 512 16B-slots
            int r = e >> 3, sr = e & 7;
            int src = (sr ^ (r & 7)) * 8;
            gload16(Brow + (size_t)r * K + k0 + src, &Bs[buf][e * 8]);
        }
    };

    STAGE(0, 0);                       // 6 loads/thread in flight
    int NK = K >> 6, cur = 0;
    for (int kt = 0; kt < NK; ++kt) {
        if (kt + 1 < NK) {
            STAGE(cur ^ 1, (kt + 1) << 6);             // +6 loads (next tile)
            asm volatile("s_waitcnt vmcnt(6)" ::: "memory");  // cur tile's 6 done; next 6 fly
        } else {
            asm volatile("s_waitcnt vmcnt(0)" ::: "memory");
        }
        __builtin_amdgcn_s_barrier();   // all waves' cur-tile loads landed
        __builtin_amdgcn_sched_barrier(0);
#pragma unroll
        for (int kk = 0; kk < 2; ++kk) {
            bf16x8 af[4], bfr[2];
#pragma unroll
            for (int m = 0; m < 4; ++m) {
                int row = wr * 64 + m * 16 + rr;
                int ss = (kk * 4 + s4) ^ (row & 7);
                af[m] = *(const bf16x8*)&As[cur][row * 64 + ss * 8];
            }
#pragma unroll
            for (int n = 0; n < 2; ++n) {
                int row = wc * 32 + n * 16 + rr;
                int ss = (kk * 4 + s4) ^ (row & 7);
                bfr[n] = *(const bf16x8*)&Bs[cur][row * 64 + ss * 8];
            }
#pragma unroll
            for (int m = 0; m < 4; ++m)
#pragma unroll
                for (int n = 0; n < 2; ++n)
                    acc[m][n] = __builtin_amdgcn_mfma_f32_16x16x32_bf16(af[m], bfr[n], acc[m][n], 0, 0, 0);
        }
        __builtin_amdgcn_s_barrier();   // protect buf[cur] before next iter's STAGE overwrites it
        cur ^= 1;
    }
    int fq = lane >> 4, fr = lane & 15;
#pragma unroll
    for (int m = 0; m < 4; ++m) {
#pragma unroll
        for (int n = 0; n < 2; ++n) {
            int col = n0 + wc * 32 + n * 16 + fr;
#pragma unroll
            for (int q = 0; q < 4; ++q) {
                int row = m0 + wr * 64 + m * 16 + fq * 4 + q;
                float v = acc[m][n][q];
                if (EPI == 0) {
                    ((u16*)Cout)[(size_t)row * ldc + col] = f2bf(v);
                } else {
                    v = v * rsl[col - n0];
                    v = v * scale[row] + shift[row];
                    v = v > 0.f ? v : 0.f;
                    // row = out-channel o, col = token (b*1024+hw)
                    ((float*)Cout)[((size_t)(col >> 10)) * (CIN * LL) + (size_t)row * LL + (col & 1023)] = v;
                }
            }
        }
    }
}

// ---------- fused: dt GEMV (blocks 0..511) | depthwise conv1d+SiLU (blocks 512..1535) ----------
// conv: 288 thr = 2 groups x 144 lanes; group handles CTT tokens, 8 ch/thread (16B loads/stores).
#define NDT (NB * LL / DTB)   // 512
__global__ __launch_bounds__(288) void convdt(const u16* __restrict__ zx,
                                              const float* __restrict__ w,
                                              const float* __restrict__ bias,
                                              u16* __restrict__ xbc,
                                              u16* __restrict__ Bc, u16* __restrict__ Cc,
                                              const u16* __restrict__ xn,
                                              const float* __restrict__ wproj,
                                              const float* __restrict__ dt_bias,
                                              const float* __restrict__ A_log,
                                              float2* __restrict__ dtda) {
    int bid = blockIdx.x;
    int t = threadIdx.x;
    if (bid < NDT) {
        // ---- dt branch (256 active threads) ----
        if (t >= 256) return;
        int h = t >> 4, part = t & 15;
        int tok0 = bid * DTB;
        const float* wr = wproj + (size_t)(DIN + DXBC + h) * CIN + part * 32;
        float4 wv[8];
#pragma unroll
        for (int i = 0; i < 8; ++i) wv[i] = *(const float4*)&wr[i * 4];
        const float* wf = (const float*)wv;
        float dtb = dt_bias[h];
        float An = -__expf(A_log[h]);
#pragma unroll
        for (int tl = 0; tl < DTB; ++tl) {
            int tok = tok0 + tl;
            const u16* xr = xn + (size_t)tok * CIN + part * 32;
            u16x8 xv0 = *(const u16x8*)&xr[0];
            u16x8 xv1 = *(const u16x8*)&xr[8];
            u16x8 xv2 = *(const u16x8*)&xr[16];
            u16x8 xv3 = *(const u16x8*)&xr[24];
            float s = 0.f;
#pragma unroll
            for (int i = 0; i < 8; ++i) s += bf2f(xv0[i]) * wf[i];
#pragma unroll
            for (int i = 0; i < 8; ++i) s += bf2f(xv1[i]) * wf[8 + i];
#pragma unroll
            for (int i = 0; i < 8; ++i) s += bf2f(xv2[i]) * wf[16 + i];
#pragma unroll
            for (int i = 0; i < 8; ++i) s += bf2f(xv3[i]) * wf[24 + i];
            s += __shfl_xor(s, 1, 64);
            s += __shfl_xor(s, 2, 64);
            s += __shfl_xor(s, 4, 64);
            s += __shfl_xor(s, 8, 64);
            if (part == 0) {
                float si = s + dtb;
                float dtv = si > 15.f ? si : __logf(1.f + __expf(si));
                float2 dd; dd.x = dtv; dd.y = dtv * An;
                dtda[(size_t)tok * NHH + h] = dd;
            }
        }
    } else {
        // ---- conv branch ----
        int cb = bid - NDT;                  // 0..1023
        int b = cb >> 7;                     // 128 blocks per batch, 8 tokens each
        int l0 = (cb & 127) * (2 * CTT);
        int grp = t < 144 ? 0 : 1;
        int u = t - grp * 144;               // 0..143
        int ch = u * 8;                      // 0..1144
        int tl0 = l0 + grp * CTT;            // batch-local first token of group

        // per-channel weights and bias (8 channels)
        float4 cw[8];
#pragma unroll
        for (int e = 0; e < 8; ++e) cw[e] = *(const float4*)&w[(ch + e) * 4];
        float bias8[8];
#pragma unroll
        for (int e = 0; e < 8; ++e) bias8[e] = bias[ch + e];

        // load CTT+3 input rows (16B each)
        u16x8 xin[CTT + 3];
        const u16* src = zx + (size_t)(b * LL + tl0 - 3) * NPADW + DIN + ch;
#pragma unroll
        for (int i = 0; i < CTT + 3; ++i) {
            u16x8 v = {0, 0, 0, 0, 0, 0, 0, 0};
            if (tl0 + i - 3 >= 0) v = *(const u16x8*)(src + (size_t)i * NPADW);
            xin[i] = v;
        }
#pragma unroll
        for (int i = 0; i < CTT; ++i) {
            int tok = b * LL + tl0 + i;
            u16x8 o;
#pragma unroll
            for (int e = 0; e < 8; ++e) {
                const float* we = (const float*)&cw[e];
                float a = bias8[e] + bf2f(xin[i][e]) * we[0] + bf2f(xin[i + 1][e]) * we[1] +
                          bf2f(xin[i + 2][e]) * we[2] + bf2f(xin[i + 3][e]) * we[3];
                o[e] = f2bf(a / (1.f + __expf(-a)));
            }
            if (ch < 1024) {
                *(u16x8*)&xbc[(size_t)tok * XBCS + ch] = o;
            } else {
                int s = ch - 1024;
                if (s < DST) *(u16x8*)&Bc[(size_t)tok * DST + s] = o;
                else         *(u16x8*)&Cc[(size_t)tok * DST + (s - DST)] = o;
            }
        }
    }
}

// ---------- SSD K1: G̃, Y_intra(bf16), ΔH(bf16), ESA, d_c ----------
__global__ __launch_bounds__(256) void ssd_chunk(const u16* __restrict__ Bcb,
                                                 const u16* __restrict__ Ccb,
                                                 const u16* __restrict__ xbc,
                                                 const float2* __restrict__ dtda,
                                                 u16* __restrict__ yi,
                                                 u16* __restrict__ DHb,
                                                 float* __restrict__ ESA,
                                                 float* __restrict__ DC) {
    __shared__ u16 Bt[4096], Ct[4096], XT[4096], BTt[4096], Gt[4096];
    __shared__ float Sar[64], dtvA[64], wA[64];
    int tau = blockIdx.x;
    int b = tau >> 8, h = (tau >> 4) & 15, c = tau & 15;
    int t0g = b * LL + c * QCH;
    int t = threadIdx.x, lane = t & 63, wave = t >> 6;
    int row = t >> 2, q = t & 3;

    {
        const u16* bp = Bcb + (size_t)(t0g + row) * DST + q * 16;
        const u16* cp = Ccb + (size_t)(t0g + row) * DST + q * 16;
        u16x8 b0v = *(const u16x8*)bp;
        u16x8 b1v = *(const u16x8*)(bp + 8);
        *(u16x8*)&Bt[swz(row, q * 32)] = b0v;
        *(u16x8*)&Bt[swz(row, q * 32 + 16)] = b1v;
        u16x8 c0v = *(const u16x8*)cp;
        u16x8 c1v = *(const u16x8*)(cp + 8);
        *(u16x8*)&Ct[swz(row, q * 32)] = c0v;
        *(u16x8*)&Ct[swz(row, q * 32 + 16)] = c1v;
        const u16* xp = xbc + (size_t)(t0g + row) * XBCS + h * HDD + q * 16;
        u16x8 x0 = *(const u16x8*)xp;
        u16x8 x1 = *(const u16x8*)(xp + 8);
#pragma unroll
        for (int e = 0; e < 8; ++e) XT[swz(q * 16 + e, row * 2)] = x0[e];
#pragma unroll
        for (int e = 0; e < 8; ++e) XT[swz(q * 16 + 8 + e, row * 2)] = x1[e];
    }
    if (t < 64) {
        float2 dd = dtda[(size_t)(t0g + t) * NHH + h];
        float s = dd.y;
#pragma unroll
        for (int off = 1; off < 64; off <<= 1) {
            float u = __shfl_up(s, off, 64);
            if (t >= off) s += u;
        }
        float SQ = __shfl(s, 63, 64);
        Sar[t] = s; dtvA[t] = dd.x;
        wA[t] = __expf(SQ - s) * dd.x;
        ESA[(size_t)tau * 64 + t] = __expf(s);
        if (t == 0) DC[tau] = __expf(SQ);
    }
    __syncthreads();

    int R = wave >> 1, Cq = wave & 1, rr = lane & 15, sg = lane >> 4;
    f32x4 g[2][2];
#pragma unroll
    for (int mi = 0; mi < 2; ++mi)
#pragma unroll
        for (int ni = 0; ni < 2; ++ni)
#pragma unroll
            for (int r = 0; r < 4; ++r) g[mi][ni][r] = 0.f;
#pragma unroll
    for (int kt = 0; kt < 2; ++kt) {
        int cb = kt * 64 + sg * 16;
        bf16x8 a0 = *(const bf16x8*)&Ct[swz(R * 32 + rr, cb)];
        bf16x8 a1 = *(const bf16x8*)&Ct[swz(R * 32 + 16 + rr, cb)];
        bf16x8 b0 = *(const bf16x8*)&Bt[swz(Cq * 32 + rr, cb)];
        bf16x8 b1 = *(const bf16x8*)&Bt[swz(Cq * 32 + 16 + rr, cb)];
        g[0][0] = __builtin_amdgcn_mfma_f32_16x16x32_bf16(a0, b0, g[0][0], 0, 0, 0);
        g[0][1] = __builtin_amdgcn_mfma_f32_16x16x32_bf16(a0, b1, g[0][1], 0, 0, 0);
        g[1][0] = __builtin_amdgcn_mfma_f32_16x16x32_bf16(a1, b0, g[1][0], 0, 0, 0);
        g[1][1] = __builtin_amdgcn_mfma_f32_16x16x32_bf16(a1, b1, g[1][1], 0, 0, 0);
    }
#pragma unroll
    for (int mi = 0; mi < 2; ++mi)
#pragma unroll
        for (int ni = 0; ni < 2; ++ni)
#pragma unroll
            for (int r = 0; r < 4; ++r) {
                int i = R * 32 + mi * 16 + sg * 4 + r;
                int j = Cq * 32 + ni * 16 + rr;
                float v = (i >= j) ? g[mi][ni][r] * __expf(Sar[i] - Sar[j]) * dtvA[j] : 0.f;
                Gt[swz(i, j * 2)] = f2bf(v);
            }
    // B~T (LDS, transposed, scaled by wA)
#pragma unroll
    for (int half = 0; half < 2; ++half) {
        u16x8 bv = *(const u16x8*)&Bt[swz(row, q * 32 + half * 16)];
#pragma unroll
        for (int e = 0; e < 8; ++e)
            BTt[swz(q * 16 + half * 8 + e, row * 2)] = f2bf(bf2f(bv[e]) * wA[row]);
    }
    __syncthreads();

    f32x4 y[2][2], dh[2][2];
#pragma unroll
    for (int mi = 0; mi < 2; ++mi)
#pragma unroll
        for (int ni = 0; ni < 2; ++ni)
#pragma unroll
            for (int r = 0; r < 4; ++r) { y[mi][ni][r] = 0.f; dh[mi][ni][r] = 0.f; }
#pragma unroll
    for (int kt = 0; kt < 2; ++kt) {
        int cb = kt * 64 + sg * 16;
        bf16x8 xb0 = *(const bf16x8*)&XT[swz(Cq * 32 + rr, cb)];
        bf16x8 xb1 = *(const bf16x8*)&XT[swz(Cq * 32 + 16 + rr, cb)];
        bf16x8 ga0 = *(const bf16x8*)&Gt[swz(R * 32 + rr, cb)];
        bf16x8 ga1 = *(const bf16x8*)&Gt[swz(R * 32 + 16 + rr, cb)];
        bf16x8 ba0 = *(const bf16x8*)&BTt[swz(R * 32 + rr, cb)];
        bf16x8 ba1 = *(const bf16x8*)&BTt[swz(R * 32 + 16 + rr, cb)];
        y[0][0] = __builtin_amdgcn_mfma_f32_16x16x32_bf16(ga0, xb0, y[0][0], 0, 0, 0);
        y[0][1] = __builtin_amdgcn_mfma_f32_16x16x32_bf16(ga0, xb1, y[0][1], 0, 0, 0);
        y[1][0] = __builtin_amdgcn_mfma_f32_16x16x32_bf16(ga1, xb0, y[1][0], 0, 0, 0);
        y[1][1] = __builtin_amdgcn_mfma_f32_16x16x32_bf16(ga1, xb1, y[1][1], 0, 0, 0);
        dh[0][0] = __builtin_amdgcn_mfma_f32_16x16x32_bf16(ba0, xb0, dh[0][0], 0, 0, 0);
        dh[0][1] = __builtin_amdgcn_mfma_f32_16x16x32_bf16(ba0, xb1, dh[0][1], 0, 0, 0);
        dh[1][0] = __builtin_amdgcn_mfma_f32_16x16x32_bf16(ba1, xb0, dh[1][0], 0, 0, 0);
        dh[1][1] = __builtin_amdgcn_mfma_f32_16x16x32_bf16(ba1, xb1, dh[1][1], 0, 0, 0);
    }
#pragma unroll
    for (int mi = 0; mi < 2; ++mi)
#pragma unroll
        for (int ni = 0; ni < 2; ++ni)
#pragma unroll
            for (int r = 0; r < 4; ++r) {
                int i = R * 32 + mi * 16 + sg * 4 + r;
                int p = Cq * 32 + ni * 16 + rr;
                yi[(size_t)(t0g + i) * DIN + h * HDD + p] = f2bf(y[mi][ni][r]);
                DHb[(size_t)tau * 4096 + i * 64 + p] = f2bf(dh[mi][ni][r]);
            }
}

// ---------- SSD K2: sequential chunk-state carry ----------
__global__ __launch_bounds__(256) void ssd_carry(const u16* __restrict__ DHb,
                                                 const float* __restrict__ DC,
                                                 u16* __restrict__ HPREV) {
    int bid = blockIdx.x;
    int bh = bid >> 1, ph = bid & 1;
    int t = threadIdx.x;
    int s = t >> 2, p0 = ph * 32 + (t & 3) * 8;
    size_t base = (size_t)bh * NCHUNK * 4096 + s * 64 + p0;
    float Hv[8] = {0.f, 0.f, 0.f, 0.f, 0.f, 0.f, 0.f, 0.f};
    for (int c = 0; c < NCHUNK; ++c) {
        size_t off = base + (size_t)c * 4096;
        u16x8 hp;
#pragma unroll
        for (int e = 0; e < 8; ++e) hp[e] = f2bf(Hv[e]);
        *(u16x8*)&HPREV[off] = hp;
        float d = DC[bh * NCHUNK + c];
        u16x8 dv = *(const u16x8*)&DHb[off];
#pragma unroll
        for (int e = 0; e < 8; ++e) Hv[e] = d * Hv[e] + bf2f(dv[e]);
    }
}

// ---------- SSD K3: Y = Y_intra + (C·eS)·Hprev; fuse D·x, z-gate; emit per-tau y² partials ----------
__global__ __launch_bounds__(256) void ssd_final(const u16* __restrict__ Ccb,
                                                 const float* __restrict__ ESA,
                                                 const u16* __restrict__ HPREV,
                                                 const u16* __restrict__ xbc,
                                                 const u16* __restrict__ zx,
                                                 const float* __restrict__ Dp,
                                                 u16* __restrict__ yi,
                                                 float* __restrict__ PS) {
    __shared__ u16 C2t[4096], HT[4096];
    __shared__ float smem_ps[2][64];
    int tau = blockIdx.x;
    int b = tau >> 8, h = (tau >> 4) & 15, c = tau & 15;
    int t0g = b * LL + c * QCH;
    int t = threadIdx.x, lane = t & 63, wave = t >> 6;
    int row = t >> 2, q = t & 3;
    {
        float esa = ESA[(size_t)tau * 64 + row];
        const u16* cp = Ccb + (size_t)(t0g + row) * DST + q * 16;
#pragma unroll
        for (int half = 0; half < 2; ++half) {
            u16x8 cv = *(const u16x8*)(cp + half * 8);
            u16x8 oc;
#pragma unroll
            for (int e = 0; e < 8; ++e) oc[e] = f2bf(bf2f(cv[e]) * esa);
            *(u16x8*)&C2t[swz(row, q * 32 + half * 16)] = oc;
            u16x8 hv = *(const u16x8*)&HPREV[(size_t)tau * 4096 + row * 64 + q * 16 + half * 8];
#pragma unroll
            for (int e = 0; e < 8; ++e) HT[swz(q * 16 + half * 8 + e, row * 2)] = hv[e];
        }
    }
    __syncthreads();
    int R = wave >> 1, Cq = wave & 1, rr = lane & 15, sg = lane >> 4;
    float Dh = Dp[h];
    f32x4 acc[2][2];
#pragma unroll
    for (int mi = 0; mi < 2; ++mi)
#pragma unroll
        for (int ni = 0; ni < 2; ++ni)
#pragma unroll
            for (int r = 0; r < 4; ++r) {
                int i = R * 32 + mi * 16 + sg * 4 + r;
                int p = Cq * 32 + ni * 16 + rr;
                acc[mi][ni][r] = bf2f(yi[(size_t)(t0g + i) * DIN + h * HDD + p]);
            }
#pragma unroll
    for (int kt = 0; kt < 2; ++kt) {
        int cb = kt * 64 + sg * 16;
        bf16x8 a0 = *(const bf16x8*)&C2t[swz(R * 32 + rr, cb)];
        bf16x8 a1 = *(const bf16x8*)&C2t[swz(R * 32 + 16 + rr, cb)];
        bf16x8 b0 = *(const bf16x8*)&HT[swz(Cq * 32 + rr, cb)];
        bf16x8 b1 = *(const bf16x8*)&HT[swz(Cq * 32 + 16 + rr, cb)];
        acc[0][0] = __builtin_amdgcn_mfma_f32_16x16x32_bf16(a0, b0, acc[0][0], 0, 0, 0);
        acc[0][1] = __builtin_amdgcn_mfma_f32_16x16x32_bf16(a0, b1, acc[0][1], 0, 0, 0);
        acc[1][0] = __builtin_amdgcn_mfma_f32_16x16x32_bf16(a1, b0, acc[1][0], 0, 0, 0);
        acc[1][1] = __builtin_amdgcn_mfma_f32_16x16x32_bf16(a1, b1, acc[1][1], 0, 0, 0);
    }
    float ps[2][4];
#pragma unroll
    for (int mi = 0; mi < 2; ++mi)
#pragma unroll
        for (int r = 0; r < 4; ++r) ps[mi][r] = 0.f;
#pragma unroll
    for (int mi = 0; mi < 2; ++mi)
#pragma unroll
        for (int ni = 0; ni < 2; ++ni)
#pragma unroll
            for (int r = 0; r < 4; ++r) {
                int i = R * 32 + mi * 16 + sg * 4 + r;
                int p = Cq * 32 + ni * 16 + rr;
                size_t tok = t0g + i;
                int col = h * HDD + p;
                float xf = bf2f(xbc[tok * XBCS + col]);
                float zf = bf2f(zx[tok * NPADW + col]);
                float yo = (acc[mi][ni][r] + Dh * xf) * (zf / (1.f + __expf(-zf)));
                yi[tok * DIN + col] = f2bf(yo);
                ps[mi][r] += yo * yo;
            }
#pragma unroll
    for (int mi = 0; mi < 2; ++mi)
#pragma unroll
        for (int r = 0; r < 4; ++r) {
            float s2 = ps[mi][r];
            s2 += __shfl_xor(s2, 1, 64);
            s2 += __shfl_xor(s2, 2, 64);
            s2 += __shfl_xor(s2, 4, 64);
            s2 += __shfl_xor(s2, 8, 64);
            if (rr == 0) smem_ps[Cq][R * 32 + mi * 16 + sg * 4 + r] = s2;
        }
    __syncthreads();
    if (t < 64) PS[(size_t)tau * 64 + t] = smem_ps[0][t] + smem_ps[1][t];
}

extern "C" void kernel_launch(void* const* d_in, const int* in_sizes, int n_in,
                              void* d_out, int out_size, void* d_ws, size_t ws_size,
                              hipStream_t stream) {
    const float* x         = (const float*)d_in[0];
    const float* ln_w      = (const float*)d_in[1];
    const float* ln_b      = (const float*)d_in[2];
    const float* in_proj_w = (const float*)d_in[3];
    const float* conv1d_w  = (const float*)d_in[4];
    const float* conv1d_b  = (const float*)d_in[5];
    const float* dt_bias   = (const float*)d_in[6];
    const float* A_log     = (const float*)d_in[7];
    const float* Dp        = (const float*)d_in[8];
    const float* rms_w     = (const float*)d_in[9];
    const float* out_proj_w= (const float*)d_in[10];
    const float* conv2d_w  = (const float*)d_in[11];
    const float* conv2d_b  = (const float*)d_in[12];
    const float* bn_g      = (const float*)d_in[13];
    const float* bn_b      = (const float*)d_in[14];
    const float* bn_mean   = (const float*)d_in[15];
    const float* bn_var    = (const float*)d_in[16];

    const int TOK = NB * LL;  // 8192
    const int NTAU = NB * NHH * NCHUNK;  // 2048
    char* ws = (char*)d_ws;
    size_t off = 0;
    auto alloc = [&](size_t bytes) {
        void* p = ws + off;
        off += (bytes + 255) & ~(size_t)255;
        return p;
    };
    u16*   Win   = (u16*)alloc((size_t)NPADW * CIN * 2);
    u16*   WoutT = (u16*)alloc((size_t)DIN * CIN * 2);
    u16*   Wc2   = (u16*)alloc((size_t)CIN * CIN * 2);
    u16*   WCMB  = (u16*)alloc((size_t)CIN * DIN * 2);
    u16*   XN    = (u16*)alloc((size_t)TOK * CIN * 2);
    u16*   ZX    = (u16*)alloc((size_t)TOK * NPADW * 2);
    u16*   XBC   = (u16*)alloc((size_t)TOK * XBCS * 2);
    u16*   Bcb   = (u16*)alloc((size_t)TOK * DST * 2);
    u16*   Ccb   = (u16*)alloc((size_t)TOK * DST * 2);
    float2* DTDA = (float2*)alloc((size_t)TOK * NHH * 8);
    u16*   YI    = (u16*)alloc((size_t)TOK * DIN * 2);
    u16*   DHb   = (u16*)alloc((size_t)NTAU * 4096 * 2);
    u16*   HPREV = (u16*)alloc((size_t)NTAU * 4096 * 2);
    float* ESA   = (float*)alloc((size_t)NTAU * 64 * 4);
    float* PS    = (float*)alloc((size_t)NTAU * 64 * 4);
    float* DC    = (float*)alloc((size_t)NTAU * 4);
    float* BNSC  = (float*)alloc(CIN * 4);
    float* BNSH  = (float*)alloc(CIN * 4);

    // fused weight prep
    prep_all<<<PREP_WIN_BLKS + PREP_WC2_BLKS + 2, 256, 0, stream>>>(
        in_proj_w, Win, conv2d_w, Wc2, conv2d_b, bn_g, bn_b, bn_mean, bn_var, BNSC, BNSH);
    woutT_conv<<<128, 256, 0, stream>>>(out_proj_w, rms_w, WoutT);
    // W_comb[o][d] = sum_c Wc2[o][c] * WoutT[d][c]   (M=512, N=1024, K=512)
    gemm_bt<0><<<(CIN / 128) * (DIN / 64), 256, 0, stream>>>(Wc2, WoutT, WCMB, CIN, DIN, CIN, DIN,
                                                             DIN / 64, nullptr, nullptr, nullptr);

    ln_kernel<<<256, 256, 0, stream>>>(x, ln_w, ln_b, XN);

    // in_proj: only the NUSE=2176 consumed columns (z + xBC)
    gemm_bt<0><<<(TOK / 128) * (NUSE / 64), 256, 0, stream>>>(XN, Win, ZX, TOK, NUSE, CIN, NPADW,
                                                              NUSE / 64, nullptr, nullptr, nullptr);

    // fused dt (first) + conv1d (16B-lane, 8 tokens/block)
    convdt<<<NDT + NB * LL / (2 * CTT), 288, 0, stream>>>(ZX, conv1d_w, conv1d_b, XBC, Bcb, Ccb,
                                                          XN, in_proj_w, dt_bias, A_log, DTDA);

    ssd_chunk<<<NTAU, 256, 0, stream>>>(Bcb, Ccb, XBC, DTDA, YI, DHb, ESA, DC);
    ssd_carry<<<256, 256, 0, stream>>>(DHb, DC, HPREV);
    ssd_final<<<NTAU, 256, 0, stream>>>(Ccb, ESA, HPREV, XBC, ZX, Dp, YI, PS);

    // fused out_proj + conv2d + BN + ReLU (per-token rms computed in-kernel from PS)
    gemm_bt<1><<<(CIN / 128) * (TOK / 64), 256, 0, stream>>>(WCMB, YI, d_out, CIN, TOK, DIN, 0,
                                                             TOK / 64, BNSC, BNSH, PS);
}

// Round 19
// 145.020 us; speedup vs baseline: 1.0232x; 1.0232x over previous
//
#include <hip/hip_runtime.h>
#include <hip/hip_bf16.h>

// Problem constants
#define NB 8
#define LL 1024        // H*W tokens per batch
#define CIN 512
#define DIN 1024       // d_inner
#define DXBC 1152      // d_inner + 2*d_state
#define DPROJ 2192     // actual in_proj rows
#define NPADW 2304     // ZX row stride (padded)
#define NUSE 2176      // cols of ZX actually consumed (z + xBC); 34 x 64
#define NHH 16
#define HDD 64
#define DST 64
#define NCHUNK 16
#define QCH 64         // chunk length
#define XBCS 1024      // XBC stored stride (x-part only)
#define CVT 16         // conv tokens per block (LDS-staged)
#define DTB 16         // dt tokens per block

typedef unsigned short u16;
typedef unsigned int u32;
typedef __bf16 bf16x8 __attribute__((ext_vector_type(8)));
typedef float f32x4 __attribute__((ext_vector_type(4)));
typedef u16 u16x8 __attribute__((ext_vector_type(8)));
typedef u16 u16x4 __attribute__((ext_vector_type(4)));

__device__ __forceinline__ float bf2f(u16 u) {
    u32 x = ((u32)u) << 16; float f; __builtin_memcpy(&f, &x, 4); return f;
}
__device__ __forceinline__ u16 f2bf(float f) {
    u32 x; __builtin_memcpy(&x, &f, 4);
    u32 r = x + 0x7fff + ((x >> 16) & 1);
    return (u16)(r >> 16);
}

__device__ __forceinline__ void gload16(const u16* g, u16* l) {
    __builtin_amdgcn_global_load_lds((__attribute__((address_space(1))) void*)(g),
                                     (__attribute__((address_space(3))) void*)(l), 16, 0, 0);
}

// swizzled u16 index into a [64][64] bf16 LDS tile (128B rows, 16B-slot XOR swizzle)
__device__ __forceinline__ int swz(int row, int cb) {
    return row * 64 + ((cb ^ ((row & 7) << 4)) >> 1);
}

// ---------- fused weight prep: Win pad-convert | Wc2 convert | BN prep ----------
#define PREP_WIN_BLKS 4608   // NPADW*CIN/256
#define PREP_WC2_BLKS 1024   // CIN*CIN/256
__global__ __launch_bounds__(256) void prep_all(const float* __restrict__ ipw, u16* __restrict__ Win,
                                                const float* __restrict__ c2w, u16* __restrict__ Wc2,
                                                const float* __restrict__ cb, const float* __restrict__ g,
                                                const float* __restrict__ bb, const float* __restrict__ mean,
                                                const float* __restrict__ var,
                                                float* __restrict__ scale, float* __restrict__ shift) {
    int bid = blockIdx.x;
    if (bid < PREP_WIN_BLKS) {
        int i = bid * 256 + threadIdx.x;
        Win[i] = (i < DPROJ * CIN) ? f2bf(ipw[i]) : (u16)0;
    } else if (bid < PREP_WIN_BLKS + PREP_WC2_BLKS) {
        int i = (bid - PREP_WIN_BLKS) * 256 + threadIdx.x;
        Wc2[i] = f2bf(c2w[i]);
    } else {
        int i = (bid - PREP_WIN_BLKS - PREP_WC2_BLKS) * 256 + threadIdx.x;
        if (i < CIN) {
            float rs = rsqrtf(var[i] + 1e-5f);
            float sc = g[i] * rs;
            scale[i] = sc;
            shift[i] = (cb[i] - mean[i]) * sc + bb[i];
        }
    }
}

// WoutT[d][c] = out_proj_w[c][d] * rms_w[d]   (LDS-tiled transpose, 64x64 tiles)
__global__ __launch_bounds__(256) void woutT_conv(const float* __restrict__ s,
                                                  const float* __restrict__ rw,
                                                  u16* __restrict__ dt) {
    __shared__ float tile[64][65];
    int bc = blockIdx.x & 7, bd = blockIdx.x >> 3;
    int c0 = bc * 64, d0 = bd * 64;
    int t = threadIdx.x;
    int r4 = t >> 6, cc = t & 63;
#pragma unroll
    for (int rr = 0; rr < 16; ++rr) {
        int row = r4 * 16 + rr;
        tile[row][cc] = s[(size_t)(c0 + row) * DIN + d0 + cc];
    }
    __syncthreads();
#pragma unroll
    for (int rr = 0; rr < 16; ++rr) {
        int row = r4 * 16 + rr;
        dt[(size_t)(d0 + row) * CIN + c0 + cc] = f2bf(tile[cc][row] * rw[d0 + row]);
    }
}

// ---------- LayerNorm over channels + transpose (B,C,HW) -> (tok, C) bf16 ----------
__global__ __launch_bounds__(256) void ln_kernel(const float* __restrict__ x,
                                                 const float* __restrict__ lw,
                                                 const float* __restrict__ lb,
                                                 u16* __restrict__ xn) {
    __shared__ u16 tile[CIN * 33];
    __shared__ float psum[8][32], psq[8][32], muA[32], rsA[32];
    int bid = blockIdx.x;
    int b = bid >> 5, hw0 = (bid & 31) * 32;
    int t = threadIdx.x;
    int hw = t & 31, cg = t >> 5;
    const float* xb = x + (size_t)b * CIN * LL + hw0 + hw;
    float s = 0.f, sq = 0.f;
    for (int r = 0; r < CIN / 8; ++r) {
        int c = r * 8 + cg;
        float v = xb[(size_t)c * LL];
        s += v; sq += v * v;
        tile[c * 33 + hw] = f2bf(v);
    }
    psum[cg][hw] = s; psq[cg][hw] = sq;
    __syncthreads();
    if (t < 32) {
        float ss = 0.f, qq = 0.f;
        for (int g = 0; g < 8; ++g) { ss += psum[g][t]; qq += psq[g][t]; }
        float mu = ss * (1.f / CIN);
        float var = qq * (1.f / CIN) - mu * mu;
        muA[t] = mu; rsA[t] = rsqrtf(var + 1e-5f);
    }
    __syncthreads();
    for (int r = 0; r < 64; ++r) {
        int idx = r * 256 + t;
        int c = idx & (CIN - 1);
        int hh = idx >> 9;
        float v = (bf2f(tile[c * 33 + hh]) - muA[hh]) * rsA[hh] * lw[c] + lb[c];
        xn[((size_t)(b * LL + hw0 + hh)) * CIN + c] = f2bf(v);
    }
}

// ---------- bf16 MFMA GEMM: 128x64 tile, BK=64, XOR-swizzled LDS, 2-phase counted vmcnt ----------
// EPI 0: bf16 store row-major ldc.
// EPI 1: v*rs(col from PS) -> BN(scale/shift[row]) -> ReLU -> remapped f32 store (d_out layout).
template <int EPI>
__global__ __launch_bounds__(256) void gemm_bt(const u16* __restrict__ A, const u16* __restrict__ Bw,
                                               void* __restrict__ Cout, int M, int N, int K, int ldc,
                                               int nx,
                                               const float* __restrict__ scale,
                                               const float* __restrict__ shift,
                                               const float* __restrict__ PS) {
    __shared__ u16 As[2][128 * 64], Bs[2][64 * 64];
    __shared__ float rsl[64];
    int t = threadIdx.x;
    int lane = t & 63, wave = t >> 6;
    // bijective XCD swizzle (m204)
    int nblk = gridDim.x;
    int qq = nblk >> 3, rm = nblk & 7;
    int xcd = blockIdx.x & 7, idx = blockIdx.x >> 3;
    int swzb = (xcd < rm ? xcd * (qq + 1) : rm * (qq + 1) + (xcd - rm) * qq) + idx;
    int m0 = (swzb / nx) * 128, n0 = (swzb % nx) * 64;
    int wr = wave >> 1, wc = wave & 1;
    f32x4 acc[4][2];
    for (int m = 0; m < 4; ++m)
        for (int n = 0; n < 2; ++n)
            for (int q = 0; q < 4; ++q) acc[m][n][q] = 0.f;

    if (EPI == 1) {
        if (t < 64) {
            int tok = n0 + t;
            int b = tok >> 10, rem = tok & 1023;
            int c = rem >> 6, ii = rem & 63;
            float s = 0.f;
#pragma unroll
            for (int h = 0; h < NHH; ++h)
                s += PS[(size_t)(((b << 4) + h) * 16 + c) * 64 + ii];
            rsl[t] = rsqrtf(s * (1.f / DIN) + 1e-5f);
        }
        __syncthreads();
    }

    const u16* Arow = A + (size_t)m0 * K;
    const u16* Brow = Bw + (size_t)n0 * K;
    int s4 = lane >> 4;
    int rr = lane & 15;

    auto STAGE = [&](int buf, int k0) {
#pragma unroll
        for (int j = 0; j < 4; ++j) {
            int e = j * 256 + t;          // A: 1024 16B-slots, 8 per row
            int r = e >> 3, sr = e & 7;
            int src = (sr ^ (r & 7)) * 8;
            gload16(Arow + (size_t)r * K + k0 + src, &As[buf][e * 8]);
        }
#pragma unroll
        for (int j = 0; j < 2; ++j) {
            int e = j * 256 + t;          // B: 512 16B-slots
            int r = e >> 3, sr = e & 7;
            int src = (sr ^ (r & 7)) * 8;
            gload16(Brow + (size_t)r * K + k0 + src, &Bs[buf][e * 8]);
        }
    };

    STAGE(0, 0);                       // 6 loads/thread in flight
    int NK = K >> 6, cur = 0;
    for (int kt = 0; kt < NK; ++kt) {
        if (kt + 1 < NK) {
            STAGE(cur ^ 1, (kt + 1) << 6);             // +6 loads (next tile)
            asm volatile("s_waitcnt vmcnt(6)" ::: "memory");  // cur tile's 6 done; next 6 fly
        } else {
            asm volatile("s_waitcnt vmcnt(0)" ::: "memory");
        }
        __builtin_amdgcn_s_barrier();   // all waves' cur-tile loads landed
        __builtin_amdgcn_sched_barrier(0);
#pragma unroll
        for (int kk = 0; kk < 2; ++kk) {
            bf16x8 af[4], bfr[2];
#pragma unroll
            for (int m = 0; m < 4; ++m) {
                int row = wr * 64 + m * 16 + rr;
                int ss = (kk * 4 + s4) ^ (row & 7);
                af[m] = *(const bf16x8*)&As[cur][row * 64 + ss * 8];
            }
#pragma unroll
            for (int n = 0; n < 2; ++n) {
                int row = wc * 32 + n * 16 + rr;
                int ss = (kk * 4 + s4) ^ (row & 7);
                bfr[n] = *(const bf16x8*)&Bs[cur][row * 64 + ss * 8];
            }
#pragma unroll
            for (int m = 0; m < 4; ++m)
#pragma unroll
                for (int n = 0; n < 2; ++n)
                    acc[m][n] = __builtin_amdgcn_mfma_f32_16x16x32_bf16(af[m], bfr[n], acc[m][n], 0, 0, 0);
        }
        __builtin_amdgcn_s_barrier();   // protect buf[cur] before next iter's STAGE overwrites it
        cur ^= 1;
    }
    int fq = lane >> 4, fr = lane & 15;
#pragma unroll
    for (int m = 0; m < 4; ++m) {
#pragma unroll
        for (int n = 0; n < 2; ++n) {
            int col = n0 + wc * 32 + n * 16 + fr;
#pragma unroll
            for (int q = 0; q < 4; ++q) {
                int row = m0 + wr * 64 + m * 16 + fq * 4 + q;
                float v = acc[m][n][q];
                if (EPI == 0) {
                    ((u16*)Cout)[(size_t)row * ldc + col] = f2bf(v);
                } else {
                    v = v * rsl[col - n0];
                    v = v * scale[row] + shift[row];
                    v = v > 0.f ? v : 0.f;
                    // row = out-channel o, col = token (b*1024+hw)
                    ((float*)Cout)[((size_t)(col >> 10)) * (CIN * LL) + (size_t)row * LL + (col & 1023)] = v;
                }
            }
        }
    }
}

// ---------- fused: LDS-staged conv1d+SiLU (blocks 0..511) | dt GEMV (blocks 512..1023) ----------
// conv: 256 threads; stage 19 rows x 1152 ch into LDS via global_load_lds (NO divergence:
// halo rows clamped to row 0 then zeroed after the barrier -- rule #21 / m104).
#define NCONV (NB * LL / CVT)   // 512
__global__ __launch_bounds__(256) void convdt(const u16* __restrict__ zx,
                                              const float* __restrict__ w,
                                              const float* __restrict__ bias,
                                              u16* __restrict__ xbc,
                                              u16* __restrict__ Bc, u16* __restrict__ Cc,
                                              const u16* __restrict__ xn,
                                              const float* __restrict__ wproj,
                                              const float* __restrict__ dt_bias,
                                              const float* __restrict__ A_log,
                                              float2* __restrict__ dtda) {
    __shared__ u16 zbuf[(CVT + 3) * DXBC];   // 19*1152*2 = 43776 B
    int bid = blockIdx.x;
    int t = threadIdx.x;
    if (bid < NCONV) {
        // ---- conv branch ----
        int b = bid >> 6;                  // 64 blocks per batch
        int l0 = (bid & 63) * CVT;
        // stage: 2736 16B-slots; slot e -> (row = e/144, 8-ch group = e%144).
        // ALL lanes always issue gload16 (clamped l) -> exec mask is a lane-0 prefix
        // in every iteration -> linear LDS writes are correct.
        for (int e = t; e < (CVT + 3) * 144; e += 256) {
            int row = e / 144, c8 = e % 144;
            int l = l0 - 3 + row;
            int lc = l < 0 ? 0 : l;
            gload16(zx + (size_t)(b * LL + lc) * NPADW + DIN + c8 * 8, &zbuf[e * 8]);
        }
        __syncthreads();                   // drains vmcnt -> all staged
        if (l0 == 0) {                     // zero halo rows 0..2 (l = -3..-1)
            for (int e = t; e < 3 * 144; e += 256) {
                u16x8 z = {0, 0, 0, 0, 0, 0, 0, 0};
                *(u16x8*)&zbuf[e * 8] = z;
            }
            __syncthreads();
        }
        // compute: thread owns 4 channels (t*4); threads 0..31 also own B/C ch 1024+t*4
#pragma unroll
        for (int pass = 0; pass < 2; ++pass) {
            if (pass == 1 && t >= 32) break;
            int ch = pass == 0 ? t * 4 : 1024 + t * 4;
            float4 cw0 = *(const float4*)&w[(ch + 0) * 4];
            float4 cw1 = *(const float4*)&w[(ch + 1) * 4];
            float4 cw2 = *(const float4*)&w[(ch + 2) * 4];
            float4 cw3 = *(const float4*)&w[(ch + 3) * 4];
            float4 bv = *(const float4*)&bias[ch];
            u16x4 win[CVT + 3];
#pragma unroll
            for (int r = 0; r < CVT + 3; ++r)
                win[r] = *(const u16x4*)&zbuf[r * DXBC + ch];
#pragma unroll
            for (int i = 0; i < CVT; ++i) {
                int tok = b * LL + l0 + i;
                float a0 = bv.x + bf2f(win[i][0]) * cw0.x + bf2f(win[i + 1][0]) * cw0.y +
                           bf2f(win[i + 2][0]) * cw0.z + bf2f(win[i + 3][0]) * cw0.w;
                float a1 = bv.y + bf2f(win[i][1]) * cw1.x + bf2f(win[i + 1][1]) * cw1.y +
                           bf2f(win[i + 2][1]) * cw1.z + bf2f(win[i + 3][1]) * cw1.w;
                float a2 = bv.z + bf2f(win[i][2]) * cw2.x + bf2f(win[i + 1][2]) * cw2.y +
                           bf2f(win[i + 2][2]) * cw2.z + bf2f(win[i + 3][2]) * cw2.w;
                float a3 = bv.w + bf2f(win[i][3]) * cw3.x + bf2f(win[i + 1][3]) * cw3.y +
                           bf2f(win[i + 2][3]) * cw3.z + bf2f(win[i + 3][3]) * cw3.w;
                ushort4 o;
                o.x = f2bf(a0 / (1.f + __expf(-a0)));
                o.y = f2bf(a1 / (1.f + __expf(-a1)));
                o.z = f2bf(a2 / (1.f + __expf(-a2)));
                o.w = f2bf(a3 / (1.f + __expf(-a3)));
                if (pass == 0) {
                    *(ushort4*)&xbc[(size_t)tok * XBCS + ch] = o;
                } else {
                    int s = ch - 1024;
                    if (s < DST) *(ushort4*)&Bc[(size_t)tok * DST + s] = o;
                    else         *(ushort4*)&Cc[(size_t)tok * DST + (s - DST)] = o;
                }
            }
        }
    } else {
        // ---- dt branch ----
        int h = t >> 4, part = t & 15;
        int tok0 = (bid - NCONV) * DTB;
        const float* wr = wproj + (size_t)(DIN + DXBC + h) * CIN + part * 32;
        float4 wv[8];
#pragma unroll
        for (int i = 0; i < 8; ++i) wv[i] = *(const float4*)&wr[i * 4];
        const float* wf = (const float*)wv;
        float dtb = dt_bias[h];
        float An = -__expf(A_log[h]);
#pragma unroll
        for (int tl = 0; tl < DTB; ++tl) {
            int tok = tok0 + tl;
            const u16* xr = xn + (size_t)tok * CIN + part * 32;
            u16x8 xv0 = *(const u16x8*)&xr[0];
            u16x8 xv1 = *(const u16x8*)&xr[8];
            u16x8 xv2 = *(const u16x8*)&xr[16];
            u16x8 xv3 = *(const u16x8*)&xr[24];
            float s = 0.f;
#pragma unroll
            for (int i = 0; i < 8; ++i) s += bf2f(xv0[i]) * wf[i];
#pragma unroll
            for (int i = 0; i < 8; ++i) s += bf2f(xv1[i]) * wf[8 + i];
#pragma unroll
            for (int i = 0; i < 8; ++i) s += bf2f(xv2[i]) * wf[16 + i];
#pragma unroll
            for (int i = 0; i < 8; ++i) s += bf2f(xv3[i]) * wf[24 + i];
            s += __shfl_xor(s, 1, 64);
            s += __shfl_xor(s, 2, 64);
            s += __shfl_xor(s, 4, 64);
            s += __shfl_xor(s, 8, 64);
            if (part == 0) {
                float si = s + dtb;
                float dtv = si > 15.f ? si : __logf(1.f + __expf(si));
                float2 dd; dd.x = dtv; dd.y = dtv * An;
                dtda[(size_t)tok * NHH + h] = dd;
            }
        }
    }
}

// ---------- SSD K1: G̃, Y_intra(bf16), ΔH(bf16), ESA, d_c ----------
__global__ __launch_bounds__(256) void ssd_chunk(const u16* __restrict__ Bcb,
                                                 const u16* __restrict__ Ccb,
                                                 const u16* __restrict__ xbc,
                                                 const float2* __restrict__ dtda,
                                                 u16* __restrict__ yi,
                                                 u16* __restrict__ DHb,
                                                 float* __restrict__ ESA,
                                                 float* __restrict__ DC) {
    __shared__ u16 Bt[4096], Ct[4096], XT[4096], BTt[4096], Gt[4096];
    __shared__ float Sar[64], dtvA[64], wA[64];
    int tau = blockIdx.x;
    int b = tau >> 8, h = (tau >> 4) & 15, c = tau & 15;
    int t0g = b * LL + c * QCH;
    int t = threadIdx.x, lane = t & 63, wave = t >> 6;
    int row = t >> 2, q = t & 3;

    {
        const u16* bp = Bcb + (size_t)(t0g + row) * DST + q * 16;
        const u16* cp = Ccb + (size_t)(t0g + row) * DST + q * 16;
        u16x8 b0v = *(const u16x8*)bp;
        u16x8 b1v = *(const u16x8*)(bp + 8);
        *(u16x8*)&Bt[swz(row, q * 32)] = b0v;
        *(u16x8*)&Bt[swz(row, q * 32 + 16)] = b1v;
        u16x8 c0v = *(const u16x8*)cp;
        u16x8 c1v = *(const u16x8*)(cp + 8);
        *(u16x8*)&Ct[swz(row, q * 32)] = c0v;
        *(u16x8*)&Ct[swz(row, q * 32 + 16)] = c1v;
        const u16* xp = xbc + (size_t)(t0g + row) * XBCS + h * HDD + q * 16;
        u16x8 x0 = *(const u16x8*)xp;
        u16x8 x1 = *(const u16x8*)(xp + 8);
#pragma unroll
        for (int e = 0; e < 8; ++e) XT[swz(q * 16 + e, row * 2)] = x0[e];
#pragma unroll
        for (int e = 0; e < 8; ++e) XT[swz(q * 16 + 8 + e, row * 2)] = x1[e];
    }
    if (t < 64) {
        float2 dd = dtda[(size_t)(t0g + t) * NHH + h];
        float s = dd.y;
#pragma unroll
        for (int off = 1; off < 64; off <<= 1) {
            float u = __shfl_up(s, off, 64);
            if (t >= off) s += u;
        }
        float SQ = __shfl(s, 63, 64);
        Sar[t] = s; dtvA[t] = dd.x;
        wA[t] = __expf(SQ - s) * dd.x;
        ESA[(size_t)tau * 64 + t] = __expf(s);
        if (t == 0) DC[tau] = __expf(SQ);
    }
    __syncthreads();

    int R = wave >> 1, Cq = wave & 1, rr = lane & 15, sg = lane >> 4;
    f32x4 g[2][2];
#pragma unroll
    for (int mi = 0; mi < 2; ++mi)
#pragma unroll
        for (int ni = 0; ni < 2; ++ni)
#pragma unroll
            for (int r = 0; r < 4; ++r) g[mi][ni][r] = 0.f;
#pragma unroll
    for (int kt = 0; kt < 2; ++kt) {
        int cb = kt * 64 + sg * 16;
        bf16x8 a0 = *(const bf16x8*)&Ct[swz(R * 32 + rr, cb)];
        bf16x8 a1 = *(const bf16x8*)&Ct[swz(R * 32 + 16 + rr, cb)];
        bf16x8 b0 = *(const bf16x8*)&Bt[swz(Cq * 32 + rr, cb)];
        bf16x8 b1 = *(const bf16x8*)&Bt[swz(Cq * 32 + 16 + rr, cb)];
        g[0][0] = __builtin_amdgcn_mfma_f32_16x16x32_bf16(a0, b0, g[0][0], 0, 0, 0);
        g[0][1] = __builtin_amdgcn_mfma_f32_16x16x32_bf16(a0, b1, g[0][1], 0, 0, 0);
        g[1][0] = __builtin_amdgcn_mfma_f32_16x16x32_bf16(a1, b0, g[1][0], 0, 0, 0);
        g[1][1] = __builtin_amdgcn_mfma_f32_16x16x32_bf16(a1, b1, g[1][1], 0, 0, 0);
    }
#pragma unroll
    for (int mi = 0; mi < 2; ++mi)
#pragma unroll
        for (int ni = 0; ni < 2; ++ni)
#pragma unroll
            for (int r = 0; r < 4; ++r) {
                int i = R * 32 + mi * 16 + sg * 4 + r;
                int j = Cq * 32 + ni * 16 + rr;
                float v = (i >= j) ? g[mi][ni][r] * __expf(Sar[i] - Sar[j]) * dtvA[j] : 0.f;
                Gt[swz(i, j * 2)] = f2bf(v);
            }
    // B~T (LDS, transposed, scaled by wA)
#pragma unroll
    for (int half = 0; half < 2; ++half) {
        u16x8 bv = *(const u16x8*)&Bt[swz(row, q * 32 + half * 16)];
#pragma unroll
        for (int e = 0; e < 8; ++e)
            BTt[swz(q * 16 + half * 8 + e, row * 2)] = f2bf(bf2f(bv[e]) * wA[row]);
    }
    __syncthreads();

    f32x4 y[2][2], dh[2][2];
#pragma unroll
    for (int mi = 0; mi < 2; ++mi)
#pragma unroll
        for (int ni = 0; ni < 2; ++ni)
#pragma unroll
            for (int r = 0; r < 4; ++r) { y[mi][ni][r] = 0.f; dh[mi][ni][r] = 0.f; }
#pragma unroll
    for (int kt = 0; kt < 2; ++kt) {
        int cb = kt * 64 + sg * 16;
        bf16x8 xb0 = *(const bf16x8*)&XT[swz(Cq * 32 + rr, cb)];
        bf16x8 xb1 = *(const bf16x8*)&XT[swz(Cq * 32 + 16 + rr, cb)];
        bf16x8 ga0 = *(const bf16x8*)&Gt[swz(R * 32 + rr, cb)];
        bf16x8 ga1 = *(const bf16x8*)&Gt[swz(R * 32 + 16 + rr, cb)];
        bf16x8 ba0 = *(const bf16x8*)&BTt[swz(R * 32 + rr, cb)];
        bf16x8 ba1 = *(const bf16x8*)&BTt[swz(R * 32 + 16 + rr, cb)];
        y[0][0] = __builtin_amdgcn_mfma_f32_16x16x32_bf16(ga0, xb0, y[0][0], 0, 0, 0);
        y[0][1] = __builtin_amdgcn_mfma_f32_16x16x32_bf16(ga0, xb1, y[0][1], 0, 0, 0);
        y[1][0] = __builtin_amdgcn_mfma_f32_16x16x32_bf16(ga1, xb0, y[1][0], 0, 0, 0);
        y[1][1] = __builtin_amdgcn_mfma_f32_16x16x32_bf16(ga1, xb1, y[1][1], 0, 0, 0);
        dh[0][0] = __builtin_amdgcn_mfma_f32_16x16x32_bf16(ba0, xb0, dh[0][0], 0, 0, 0);
        dh[0][1] = __builtin_amdgcn_mfma_f32_16x16x32_bf16(ba0, xb1, dh[0][1], 0, 0, 0);
        dh[1][0] = __builtin_amdgcn_mfma_f32_16x16x32_bf16(ba1, xb0, dh[1][0], 0, 0, 0);
        dh[1][1] = __builtin_amdgcn_mfma_f32_16x16x32_bf16(ba1, xb1, dh[1][1], 0, 0, 0);
    }
#pragma unroll
    for (int mi = 0; mi < 2; ++mi)
#pragma unroll
        for (int ni = 0; ni < 2; ++ni)
#pragma unroll
            for (int r = 0; r < 4; ++r) {
                int i = R * 32 + mi * 16 + sg * 4 + r;
                int p = Cq * 32 + ni * 16 + rr;
                yi[(size_t)(t0g + i) * DIN + h * HDD + p] = f2bf(y[mi][ni][r]);
                DHb[(size_t)tau * 4096 + i * 64 + p] = f2bf(dh[mi][ni][r]);
            }
}

// ---------- SSD K2: sequential chunk-state carry ----------
__global__ __launch_bounds__(256) void ssd_carry(const u16* __restrict__ DHb,
                                                 const float* __restrict__ DC,
                                                 u16* __restrict__ HPREV) {
    int bid = blockIdx.x;
    int bh = bid >> 1, ph = bid & 1;
    int t = threadIdx.x;
    int s = t >> 2, p0 = ph * 32 + (t & 3) * 8;
    size_t base = (size_t)bh * NCHUNK * 4096 + s * 64 + p0;
    float Hv[8] = {0.f, 0.f, 0.f, 0.f, 0.f, 0.f, 0.f, 0.f};
    for (int c = 0; c < NCHUNK; ++c) {
        size_t off = base + (size_t)c * 4096;
        u16x8 hp;
#pragma unroll
        for (int e = 0; e < 8; ++e) hp[e] = f2bf(Hv[e]);
        *(u16x8*)&HPREV[off] = hp;
        float d = DC[bh * NCHUNK + c];
        u16x8 dv = *(const u16x8*)&DHb[off];
#pragma unroll
        for (int e = 0; e < 8; ++e) Hv[e] = d * Hv[e] + bf2f(dv[e]);
    }
}

// ---------- SSD K3: Y = Y_intra + (C·eS)·Hprev; fuse D·x, z-gate; emit per-tau y² partials ----------
__global__ __launch_bounds__(256) void ssd_final(const u16* __restrict__ Ccb,
                                                 const float* __restrict__ ESA,
                                                 const u16* __restrict__ HPREV,
                                                 const u16* __restrict__ xbc,
                                                 const u16* __restrict__ zx,
                                                 const float* __restrict__ Dp,
                                                 u16* __restrict__ yi,
                                                 float* __restrict__ PS) {
    __shared__ u16 C2t[4096], HT[4096];
    __shared__ float smem_ps[2][64];
    int tau = blockIdx.x;
    int b = tau >> 8, h = (tau >> 4) & 15, c = tau & 15;
    int t0g = b * LL + c * QCH;
    int t = threadIdx.x, lane = t & 63, wave = t >> 6;
    int row = t >> 2, q = t & 3;
    {
        float esa = ESA[(size_t)tau * 64 + row];
        const u16* cp = Ccb + (size_t)(t0g + row) * DST + q * 16;
#pragma unroll
        for (int half = 0; half < 2; ++half) {
            u16x8 cv = *(const u16x8*)(cp + half * 8);
            u16x8 oc;
#pragma unroll
            for (int e = 0; e < 8; ++e) oc[e] = f2bf(bf2f(cv[e]) * esa);
            *(u16x8*)&C2t[swz(row, q * 32 + half * 16)] = oc;
            u16x8 hv = *(const u16x8*)&HPREV[(size_t)tau * 4096 + row * 64 + q * 16 + half * 8];
#pragma unroll
            for (int e = 0; e < 8; ++e) HT[swz(q * 16 + half * 8 + e, row * 2)] = hv[e];
        }
    }
    __syncthreads();
    int R = wave >> 1, Cq = wave & 1, rr = lane & 15, sg = lane >> 4;
    float Dh = Dp[h];
    f32x4 acc[2][2];
#pragma unroll
    for (int mi = 0; mi < 2; ++mi)
#pragma unroll
        for (int ni = 0; ni < 2; ++ni)
#pragma unroll
            for (int r = 0; r < 4; ++r) {
                int i = R * 32 + mi * 16 + sg * 4 + r;
                int p = Cq * 32 + ni * 16 + rr;
                acc[mi][ni][r] = bf2f(yi[(size_t)(t0g + i) * DIN + h * HDD + p]);
            }
#pragma unroll
    for (int kt = 0; kt < 2; ++kt) {
        int cb = kt * 64 + sg * 16;
        bf16x8 a0 = *(const bf16x8*)&C2t[swz(R * 32 + rr, cb)];
        bf16x8 a1 = *(const bf16x8*)&C2t[swz(R * 32 + 16 + rr, cb)];
        bf16x8 b0 = *(const bf16x8*)&HT[swz(Cq * 32 + rr, cb)];
        bf16x8 b1 = *(const bf16x8*)&HT[swz(Cq * 32 + 16 + rr, cb)];
        acc[0][0] = __builtin_amdgcn_mfma_f32_16x16x32_bf16(a0, b0, acc[0][0], 0, 0, 0);
        acc[0][1] = __builtin_amdgcn_mfma_f32_16x16x32_bf16(a0, b1, acc[0][1], 0, 0, 0);
        acc[1][0] = __builtin_amdgcn_mfma_f32_16x16x32_bf16(a1, b0, acc[1][0], 0, 0, 0);
        acc[1][1] = __builtin_amdgcn_mfma_f32_16x16x32_bf16(a1, b1, acc[1][1], 0, 0, 0);
    }
    float ps[2][4];
#pragma unroll
    for (int mi = 0; mi < 2; ++mi)
#pragma unroll
        for (int r = 0; r < 4; ++r) ps[mi][r] = 0.f;
#pragma unroll
    for (int mi = 0; mi < 2; ++mi)
#pragma unroll
        for (int ni = 0; ni < 2; ++ni)
#pragma unroll
            for (int r = 0; r < 4; ++r) {
                int i = R * 32 + mi * 16 + sg * 4 + r;
                int p = Cq * 32 + ni * 16 + rr;
                size_t tok = t0g + i;
                int col = h * HDD + p;
                float xf = bf2f(xbc[tok * XBCS + col]);
                float zf = bf2f(zx[tok * NPADW + col]);
                float yo = (acc[mi][ni][r] + Dh * xf) * (zf / (1.f + __expf(-zf)));
                yi[tok * DIN + col] = f2bf(yo);
                ps[mi][r] += yo * yo;
            }
#pragma unroll
    for (int mi = 0; mi < 2; ++mi)
#pragma unroll
        for (int r = 0; r < 4; ++r) {
            float s2 = ps[mi][r];
            s2 += __shfl_xor(s2, 1, 64);
            s2 += __shfl_xor(s2, 2, 64);
            s2 += __shfl_xor(s2, 4, 64);
            s2 += __shfl_xor(s2, 8, 64);
            if (rr == 0) smem_ps[Cq][R * 32 + mi * 16 + sg * 4 + r] = s2;
        }
    __syncthreads();
    if (t < 64) PS[(size_t)tau * 64 + t] = smem_ps[0][t] + smem_ps[1][t];
}

extern "C" void kernel_launch(void* const* d_in, const int* in_sizes, int n_in,
                              void* d_out, int out_size, void* d_ws, size_t ws_size,
                              hipStream_t stream) {
    const float* x         = (const float*)d_in[0];
    const float* ln_w      = (const float*)d_in[1];
    const float* ln_b      = (const float*)d_in[2];
    const float* in_proj_w = (const float*)d_in[3];
    const float* conv1d_w  = (const float*)d_in[4];
    const float* conv1d_b  = (const float*)d_in[5];
    const float* dt_bias   = (const float*)d_in[6];
    const float* A_log     = (const float*)d_in[7];
    const float* Dp        = (const float*)d_in[8];
    const float* rms_w     = (const float*)d_in[9];
    const float* out_proj_w= (const float*)d_in[10];
    const float* conv2d_w  = (const float*)d_in[11];
    const float* conv2d_b  = (const float*)d_in[12];
    const float* bn_g      = (const float*)d_in[13];
    const float* bn_b      = (const float*)d_in[14];
    const float* bn_mean   = (const float*)d_in[15];
    const float* bn_var    = (const float*)d_in[16];

    const int TOK = NB * LL;  // 8192
    const int NTAU = NB * NHH * NCHUNK;  // 2048
    char* ws = (char*)d_ws;
    size_t off = 0;
    auto alloc = [&](size_t bytes) {
        void* p = ws + off;
        off += (bytes + 255) & ~(size_t)255;
        return p;
    };
    u16*   Win   = (u16*)alloc((size_t)NPADW * CIN * 2);
    u16*   WoutT = (u16*)alloc((size_t)DIN * CIN * 2);
    u16*   Wc2   = (u16*)alloc((size_t)CIN * CIN * 2);
    u16*   WCMB  = (u16*)alloc((size_t)CIN * DIN * 2);
    u16*   XN    = (u16*)alloc((size_t)TOK * CIN * 2);
    u16*   ZX    = (u16*)alloc((size_t)TOK * NPADW * 2);
    u16*   XBC   = (u16*)alloc((size_t)TOK * XBCS * 2);
    u16*   Bcb   = (u16*)alloc((size_t)TOK * DST * 2);
    u16*   Ccb   = (u16*)alloc((size_t)TOK * DST * 2);
    float2* DTDA = (float2*)alloc((size_t)TOK * NHH * 8);
    u16*   YI    = (u16*)alloc((size_t)TOK * DIN * 2);
    u16*   DHb   = (u16*)alloc((size_t)NTAU * 4096 * 2);
    u16*   HPREV = (u16*)alloc((size_t)NTAU * 4096 * 2);
    float* ESA   = (float*)alloc((size_t)NTAU * 64 * 4);
    float* PS    = (float*)alloc((size_t)NTAU * 64 * 4);
    float* DC    = (float*)alloc((size_t)NTAU * 4);
    float* BNSC  = (float*)alloc(CIN * 4);
    float* BNSH  = (float*)alloc(CIN * 4);

    // fused weight prep
    prep_all<<<PREP_WIN_BLKS + PREP_WC2_BLKS + 2, 256, 0, stream>>>(
        in_proj_w, Win, conv2d_w, Wc2, conv2d_b, bn_g, bn_b, bn_mean, bn_var, BNSC, BNSH);
    woutT_conv<<<128, 256, 0, stream>>>(out_proj_w, rms_w, WoutT);
    // W_comb[o][d] = sum_c Wc2[o][c] * WoutT[d][c]   (M=512, N=1024, K=512)
    gemm_bt<0><<<(CIN / 128) * (DIN / 64), 256, 0, stream>>>(Wc2, WoutT, WCMB, CIN, DIN, CIN, DIN,
                                                             DIN / 64, nullptr, nullptr, nullptr);

    ln_kernel<<<256, 256, 0, stream>>>(x, ln_w, ln_b, XN);

    // in_proj: only the NUSE=2176 consumed columns (z + xBC)
    gemm_bt<0><<<(TOK / 128) * (NUSE / 64), 256, 0, stream>>>(XN, Win, ZX, TOK, NUSE, CIN, NPADW,
                                                              NUSE / 64, nullptr, nullptr, nullptr);

    // fused LDS-staged conv1d + dt_gemv
    convdt<<<NCONV + TOK / DTB, 256, 0, stream>>>(ZX, conv1d_w, conv1d_b, XBC, Bcb, Ccb,
                                                  XN, in_proj_w, dt_bias, A_log, DTDA);

    ssd_chunk<<<NTAU, 256, 0, stream>>>(Bcb, Ccb, XBC, DTDA, YI, DHb, ESA, DC);
    ssd_carry<<<256, 256, 0, stream>>>(DHb, DC, HPREV);
    ssd_final<<<NTAU, 256, 0, stream>>>(Ccb, ESA, HPREV, XBC, ZX, Dp, YI, PS);

    // fused out_proj + conv2d + BN + ReLU (per-token rms computed in-kernel from PS)
    gemm_bt<1><<<(CIN / 128) * (TOK / 64), 256, 0, stream>>>(WCMB, YI, d_out, CIN, TOK, DIN, 0,
                                                             TOK / 64, BNSC, BNSH, PS);
}

// Round 21
// 143.404 us; speedup vs baseline: 1.0348x; 1.0113x over previous
//
#include <hip/hip_runtime.h>
#include <hip/hip_bf16.h>

// Problem constants
#define NB 8
#define LL 1024        // H*W tokens per batch
#define CIN 512
#define DIN 1024       // d_inner
#define DXBC 1152      // d_inner + 2*d_state
#define DPROJ 2192     // actual in_proj rows
#define NPADW 2304     // ZX row stride (padded)
#define NUSE 2176      // cols of ZX actually consumed (z + xBC); 34 x 64
#define NHH 16
#define HDD 64
#define DST 64
#define NCHUNK 16
#define QCH 64         // chunk length
#define XBCS 1024      // XBC stored stride (x-part only)
#define CTT 8          // conv tokens per block
#define DTB 16         // dt tokens per block

typedef unsigned short u16;
typedef unsigned int u32;
typedef __bf16 bf16x8 __attribute__((ext_vector_type(8)));
typedef float f32x4 __attribute__((ext_vector_type(4)));
typedef u16 u16x8 __attribute__((ext_vector_type(8)));

__device__ __forceinline__ float bf2f(u16 u) {
    u32 x = ((u32)u) << 16; float f; __builtin_memcpy(&f, &x, 4); return f;
}
__device__ __forceinline__ u16 f2bf(float f) {
    u32 x; __builtin_memcpy(&x, &f, 4);
    u32 r = x + 0x7fff + ((x >> 16) & 1);
    return (u16)(r >> 16);
}

__device__ __forceinline__ void gload16(const u16* g, u16* l) {
    __builtin_amdgcn_global_load_lds((__attribute__((address_space(1))) void*)(g),
                                     (__attribute__((address_space(3))) void*)(l), 16, 0, 0);
}

// swizzled u16 index into a [64][64] bf16 LDS tile (128B rows, 16B-slot XOR swizzle)
__device__ __forceinline__ int swz(int row, int cb) {
    return row * 64 + ((cb ^ ((row & 7) << 4)) >> 1);
}

// ---------- fused weight prep: Win pad-convert | Wc2 convert | BN prep ----------
#define PREP_WIN_BLKS 4608   // NPADW*CIN/256
#define PREP_WC2_BLKS 1024   // CIN*CIN/256
__global__ __launch_bounds__(256) void prep_all(const float* __restrict__ ipw, u16* __restrict__ Win,
                                                const float* __restrict__ c2w, u16* __restrict__ Wc2,
                                                const float* __restrict__ cb, const float* __restrict__ g,
                                                const float* __restrict__ bb, const float* __restrict__ mean,
                                                const float* __restrict__ var,
                                                float* __restrict__ scale, float* __restrict__ shift) {
    int bid = blockIdx.x;
    if (bid < PREP_WIN_BLKS) {
        int i = bid * 256 + threadIdx.x;
        Win[i] = (i < DPROJ * CIN) ? f2bf(ipw[i]) : (u16)0;
    } else if (bid < PREP_WIN_BLKS + PREP_WC2_BLKS) {
        int i = (bid - PREP_WIN_BLKS) * 256 + threadIdx.x;
        Wc2[i] = f2bf(c2w[i]);
    } else {
        int i = (bid - PREP_WIN_BLKS - PREP_WC2_BLKS) * 256 + threadIdx.x;
        if (i < CIN) {
            float rs = rsqrtf(var[i] + 1e-5f);
            float sc = g[i] * rs;
            scale[i] = sc;
            shift[i] = (cb[i] - mean[i]) * sc + bb[i];
        }
    }
}

// WoutT[d][c] = out_proj_w[c][d] * rms_w[d]   (LDS-tiled transpose, 64x64 tiles)
__global__ __launch_bounds__(256) void woutT_conv(const float* __restrict__ s,
                                                  const float* __restrict__ rw,
                                                  u16* __restrict__ dt) {
    __shared__ float tile[64][65];
    int bc = blockIdx.x & 7, bd = blockIdx.x >> 3;
    int c0 = bc * 64, d0 = bd * 64;
    int t = threadIdx.x;
    int r4 = t >> 6, cc = t & 63;
#pragma unroll
    for (int rr = 0; rr < 16; ++rr) {
        int row = r4 * 16 + rr;
        tile[row][cc] = s[(size_t)(c0 + row) * DIN + d0 + cc];
    }
    __syncthreads();
#pragma unroll
    for (int rr = 0; rr < 16; ++rr) {
        int row = r4 * 16 + rr;
        dt[(size_t)(d0 + row) * CIN + c0 + cc] = f2bf(tile[cc][row] * rw[d0 + row]);
    }
}

// ---------- LayerNorm over channels + transpose (B,C,HW) -> (tok, C) bf16 ----------
__global__ __launch_bounds__(256) void ln_kernel(const float* __restrict__ x,
                                                 const float* __restrict__ lw,
                                                 const float* __restrict__ lb,
                                                 u16* __restrict__ xn) {
    __shared__ u16 tile[CIN * 33];
    __shared__ float psum[8][32], psq[8][32], muA[32], rsA[32];
    int bid = blockIdx.x;
    int b = bid >> 5, hw0 = (bid & 31) * 32;
    int t = threadIdx.x;
    int hw = t & 31, cg = t >> 5;
    const float* xb = x + (size_t)b * CIN * LL + hw0 + hw;
    float s = 0.f, sq = 0.f;
    for (int r = 0; r < CIN / 8; ++r) {
        int c = r * 8 + cg;
        float v = xb[(size_t)c * LL];
        s += v; sq += v * v;
        tile[c * 33 + hw] = f2bf(v);
    }
    psum[cg][hw] = s; psq[cg][hw] = sq;
    __syncthreads();
    if (t < 32) {
        float ss = 0.f, qq = 0.f;
        for (int g = 0; g < 8; ++g) { ss += psum[g][t]; qq += psq[g][t]; }
        float mu = ss * (1.f / CIN);
        float var = qq * (1.f / CIN) - mu * mu;
        muA[t] = mu; rsA[t] = rsqrtf(var + 1e-5f);
    }
    __syncthreads();
    for (int r = 0; r < 64; ++r) {
        int idx = r * 256 + t;
        int c = idx & (CIN - 1);
        int hh = idx >> 9;
        float v = (bf2f(tile[c * 33 + hh]) - muA[hh]) * rsA[hh] * lw[c] + lb[c];
        xn[((size_t)(b * LL + hw0 + hh)) * CIN + c] = f2bf(v);
    }
}

// ---------- bf16 MFMA GEMM: 128x64 tile, BK=64, XOR-swizzled LDS, 2-phase counted vmcnt ----------
// EPI 0: bf16 store row-major ldc.
// EPI 1: v*rs(col from PS) -> BN(scale/shift[row]) -> ReLU -> remapped f32 store (d_out layout).
template <int EPI>
__global__ __launch_bounds__(256) void gemm_bt(const u16* __restrict__ A, const u16* __restrict__ Bw,
                                               void* __restrict__ Cout, int M, int N, int K, int ldc,
                                               int nx,
                                               const float* __restrict__ scale,
                                               const float* __restrict__ shift,
                                               const float* __restrict__ PS) {
    __shared__ u16 As[2][128 * 64], Bs[2][64 * 64];
    __shared__ float rsl[64];
    int t = threadIdx.x;
    int lane = t & 63, wave = t >> 6;
    // bijective XCD swizzle (m204)
    int nblk = gridDim.x;
    int qq = nblk >> 3, rm = nblk & 7;
    int xcd = blockIdx.x & 7, idx = blockIdx.x >> 3;
    int swzb = (xcd < rm ? xcd * (qq + 1) : rm * (qq + 1) + (xcd - rm) * qq) + idx;
    int m0 = (swzb / nx) * 128, n0 = (swzb % nx) * 64;
    int wr = wave >> 1, wc = wave & 1;
    f32x4 acc[4][2];
    for (int m = 0; m < 4; ++m)
        for (int n = 0; n < 2; ++n)
            for (int q = 0; q < 4; ++q) acc[m][n][q] = 0.f;

    if (EPI == 1) {
        // per-token rms scale for this block's 64 token-columns
        if (t < 64) {
            int tok = n0 + t;
            int b = tok >> 10, rem = tok & 1023;
            int c = rem >> 6, ii = rem & 63;
            float s = 0.f;
#pragma unroll
            for (int h = 0; h < NHH; ++h)
                s += PS[(size_t)(((b << 4) + h) * 16 + c) * 64 + ii];
            rsl[t] = rsqrtf(s * (1.f / DIN) + 1e-5f);
        }
        __syncthreads();
    }

    const u16* Arow = A + (size_t)m0 * K;
    const u16* Brow = Bw + (size_t)n0 * K;
    int s4 = lane >> 4;
    int rr = lane & 15;

    auto STAGE = [&](int buf, int k0) {
#pragma unroll
        for (int j = 0; j < 4; ++j) {
            int e = j * 256 + t;          // A: 1024 16B-slots, 8 per row
            int r = e >> 3, sr = e & 7;
            int src = (sr ^ (r & 7)) * 8;
            gload16(Arow + (size_t)r * K + k0 + src, &As[buf][e * 8]);
        }
#pragma unroll
        for (int j = 0; j < 2; ++j) {
            int e = j * 256 + t;          // B: 512 16B-slots
            int r = e >> 3, sr = e & 7;
            int src = (sr ^ (r & 7)) * 8;
            gload16(Brow + (size_t)r * K + k0 + src, &Bs[buf][e * 8]);
        }
    };

    STAGE(0, 0);                       // 6 loads/thread in flight
    int NK = K >> 6, cur = 0;
    for (int kt = 0; kt < NK; ++kt) {
        if (kt + 1 < NK) {
            STAGE(cur ^ 1, (kt + 1) << 6);             // +6 loads (next tile)
            asm volatile("s_waitcnt vmcnt(6)" ::: "memory");  // cur tile's 6 done; next 6 fly
        } else {
            asm volatile("s_waitcnt vmcnt(0)" ::: "memory");
        }
        __builtin_amdgcn_s_barrier();   // all waves' cur-tile loads landed
        __builtin_amdgcn_sched_barrier(0);
#pragma unroll
        for (int kk = 0; kk < 2; ++kk) {
            bf16x8 af[4], bfr[2];
#pragma unroll
            for (int m = 0; m < 4; ++m) {
                int row = wr * 64 + m * 16 + rr;
                int ss = (kk * 4 + s4) ^ (row & 7);
                af[m] = *(const bf16x8*)&As[cur][row * 64 + ss * 8];
            }
#pragma unroll
            for (int n = 0; n < 2; ++n) {
                int row = wc * 32 + n * 16 + rr;
                int ss = (kk * 4 + s4) ^ (row & 7);
                bfr[n] = *(const bf16x8*)&Bs[cur][row * 64 + ss * 8];
            }
#pragma unroll
            for (int m = 0; m < 4; ++m)
#pragma unroll
                for (int n = 0; n < 2; ++n)
                    acc[m][n] = __builtin_amdgcn_mfma_f32_16x16x32_bf16(af[m], bfr[n], acc[m][n], 0, 0, 0);
        }
        __builtin_amdgcn_s_barrier();   // protect buf[cur] before next iter's STAGE overwrites it
        cur ^= 1;
    }
    int fq = lane >> 4, fr = lane & 15;
#pragma unroll
    for (int m = 0; m < 4; ++m) {
#pragma unroll
        for (int n = 0; n < 2; ++n) {
            int col = n0 + wc * 32 + n * 16 + fr;
#pragma unroll
            for (int q = 0; q < 4; ++q) {
                int row = m0 + wr * 64 + m * 16 + fq * 4 + q;
                float v = acc[m][n][q];
                if (EPI == 0) {
                    ((u16*)Cout)[(size_t)row * ldc + col] = f2bf(v);
                } else {
                    v = v * rsl[col - n0];
                    v = v * scale[row] + shift[row];
                    v = v > 0.f ? v : 0.f;
                    // row = out-channel o, col = token (b*1024+hw)
                    ((float*)Cout)[((size_t)(col >> 10)) * (CIN * LL) + (size_t)row * LL + (col & 1023)] = v;
                }
            }
        }
    }
}

// ---------- fused: depthwise conv1d+SiLU (blocks 0..1023) | dt GEMV (blocks 1024..1535) ----------
__global__ __launch_bounds__(288) void convdt(const u16* __restrict__ zx,
                                              const float* __restrict__ w,
                                              const float* __restrict__ bias,
                                              u16* __restrict__ xbc,
                                              u16* __restrict__ Bc, u16* __restrict__ Cc,
                                              const u16* __restrict__ xn,
                                              const float* __restrict__ wproj,
                                              const float* __restrict__ dt_bias,
                                              const float* __restrict__ A_log,
                                              float2* __restrict__ dtda) {
    int bid = blockIdx.x;
    int t = threadIdx.x;
    if (bid < NB * (LL / CTT)) {
        // ---- conv branch ----
        int b = bid >> 7;
        int l0 = (bid & 127) * CTT;
        bool isX = t < 256;
        int ch = isX ? t * 4 : 1024 + (t - 256) * 4;

        float4 wv0 = *(const float4*)&w[(ch + 0) * 4];
        float4 wv1 = *(const float4*)&w[(ch + 1) * 4];
        float4 wv2 = *(const float4*)&w[(ch + 2) * 4];
        float4 wv3 = *(const float4*)&w[(ch + 3) * 4];
        float4 bv = *(const float4*)&bias[ch];

        ushort4 xin[CTT + 3];
        const u16* src = zx + (size_t)(b * LL + l0 - 3) * NPADW + DIN + ch;
#pragma unroll
        for (int i = 0; i < CTT + 3; ++i) {
            ushort4 v = {0, 0, 0, 0};
            if (l0 + i - 3 >= 0) v = *(const ushort4*)(src + (size_t)i * NPADW);
            xin[i] = v;
        }
#pragma unroll
        for (int i = 0; i < CTT; ++i) {
            int tok = b * LL + l0 + i;
            float a0 = bv.x + bf2f(xin[i].x) * wv0.x + bf2f(xin[i + 1].x) * wv0.y +
                       bf2f(xin[i + 2].x) * wv0.z + bf2f(xin[i + 3].x) * wv0.w;
            float a1 = bv.y + bf2f(xin[i].y) * wv1.x + bf2f(xin[i + 1].y) * wv1.y +
                       bf2f(xin[i + 2].y) * wv1.z + bf2f(xin[i + 3].y) * wv1.w;
            float a2 = bv.z + bf2f(xin[i].z) * wv2.x + bf2f(xin[i + 1].z) * wv2.y +
                       bf2f(xin[i + 2].z) * wv2.z + bf2f(xin[i + 3].z) * wv2.w;
            float a3 = bv.w + bf2f(xin[i].w) * wv3.x + bf2f(xin[i + 1].w) * wv3.y +
                       bf2f(xin[i + 2].w) * wv3.z + bf2f(xin[i + 3].w) * wv3.w;
            float s0 = a0 / (1.f + __expf(-a0));
            float s1 = a1 / (1.f + __expf(-a1));
            float s2 = a2 / (1.f + __expf(-a2));
            float s3 = a3 / (1.f + __expf(-a3));
            ushort4 o;
            o.x = f2bf(s0); o.y = f2bf(s1); o.z = f2bf(s2); o.w = f2bf(s3);
            if (isX) {
                *(ushort4*)&xbc[(size_t)tok * XBCS + ch] = o;
            } else {
                int s = ch - 1024;
                if (s < DST) *(ushort4*)&Bc[(size_t)tok * DST + s] = o;
                else         *(ushort4*)&Cc[(size_t)tok * DST + (s - DST)] = o;
            }
        }
    } else {
        // ---- dt branch (256 active threads) ----
        if (t >= 256) return;
        int h = t >> 4, part = t & 15;
        int tok0 = (bid - NB * (LL / CTT)) * DTB;
        const float* wr = wproj + (size_t)(DIN + DXBC + h) * CIN + part * 32;
        float4 wv[8];
#pragma unroll
        for (int i = 0; i < 8; ++i) wv[i] = *(const float4*)&wr[i * 4];
        const float* wf = (const float*)wv;
        float dtb = dt_bias[h];
        float An = -__expf(A_log[h]);
#pragma unroll
        for (int tl = 0; tl < DTB; ++tl) {
            int tok = tok0 + tl;
            const u16* xr = xn + (size_t)tok * CIN + part * 32;
            u16x8 xv0 = *(const u16x8*)&xr[0];
            u16x8 xv1 = *(const u16x8*)&xr[8];
            u16x8 xv2 = *(const u16x8*)&xr[16];
            u16x8 xv3 = *(const u16x8*)&xr[24];
            float s = 0.f;
#pragma unroll
            for (int i = 0; i < 8; ++i) s += bf2f(xv0[i]) * wf[i];
#pragma unroll
            for (int i = 0; i < 8; ++i) s += bf2f(xv1[i]) * wf[8 + i];
#pragma unroll
            for (int i = 0; i < 8; ++i) s += bf2f(xv2[i]) * wf[16 + i];
#pragma unroll
            for (int i = 0; i < 8; ++i) s += bf2f(xv3[i]) * wf[24 + i];
            s += __shfl_xor(s, 1, 64);
            s += __shfl_xor(s, 2, 64);
            s += __shfl_xor(s, 4, 64);
            s += __shfl_xor(s, 8, 64);
            if (part == 0) {
                float si = s + dtb;
                float dtv = si > 15.f ? si : __logf(1.f + __expf(si));
                float2 dd; dd.x = dtv; dd.y = dtv * An;
                dtda[(size_t)tok * NHH + h] = dd;
            }
        }
    }
}

// ---------- SSD K1: G̃, Y_intra(bf16), ΔH(bf16), ESA, d_c ----------
__global__ __launch_bounds__(256) void ssd_chunk(const u16* __restrict__ Bcb,
                                                 const u16* __restrict__ Ccb,
                                                 const u16* __restrict__ xbc,
                                                 const float2* __restrict__ dtda,
                                                 u16* __restrict__ yi,
                                                 u16* __restrict__ DHb,
                                                 float* __restrict__ ESA,
                                                 float* __restrict__ DC) {
    __shared__ u16 Bt[4096], Ct[4096], XT[4096], BTt[4096], Gt[4096];
    __shared__ float Sar[64], dtvA[64], wA[64];
    int tau = blockIdx.x;
    int b = tau >> 8, h = (tau >> 4) & 15, c = tau & 15;
    int t0g = b * LL + c * QCH;
    int t = threadIdx.x, lane = t & 63, wave = t >> 6;
    int row = t >> 2, q = t & 3;

    {
        const u16* bp = Bcb + (size_t)(t0g + row) * DST + q * 16;
        const u16* cp = Ccb + (size_t)(t0g + row) * DST + q * 16;
        u16x8 b0v = *(const u16x8*)bp;
        u16x8 b1v = *(const u16x8*)(bp + 8);
        *(u16x8*)&Bt[swz(row, q * 32)] = b0v;
        *(u16x8*)&Bt[swz(row, q * 32 + 16)] = b1v;
        u16x8 c0v = *(const u16x8*)cp;
        u16x8 c1v = *(const u16x8*)(cp + 8);
        *(u16x8*)&Ct[swz(row, q * 32)] = c0v;
        *(u16x8*)&Ct[swz(row, q * 32 + 16)] = c1v;
        const u16* xp = xbc + (size_t)(t0g + row) * XBCS + h * HDD + q * 16;
        u16x8 x0 = *(const u16x8*)xp;
        u16x8 x1 = *(const u16x8*)(xp + 8);
#pragma unroll
        for (int e = 0; e < 8; ++e) XT[swz(q * 16 + e, row * 2)] = x0[e];
#pragma unroll
        for (int e = 0; e < 8; ++e) XT[swz(q * 16 + 8 + e, row * 2)] = x1[e];
    }
    if (t < 64) {
        float2 dd = dtda[(size_t)(t0g + t) * NHH + h];
        float s = dd.y;
#pragma unroll
        for (int off = 1; off < 64; off <<= 1) {
            float u = __shfl_up(s, off, 64);
            if (t >= off) s += u;
        }
        float SQ = __shfl(s, 63, 64);
        Sar[t] = s; dtvA[t] = dd.x;
        wA[t] = __expf(SQ - s) * dd.x;
        ESA[(size_t)tau * 64 + t] = __expf(s);
        if (t == 0) DC[tau] = __expf(SQ);
    }
    __syncthreads();

    int R = wave >> 1, Cq = wave & 1, rr = lane & 15, sg = lane >> 4;
    f32x4 g[2][2];
#pragma unroll
    for (int mi = 0; mi < 2; ++mi)
#pragma unroll
        for (int ni = 0; ni < 2; ++ni)
#pragma unroll
            for (int r = 0; r < 4; ++r) g[mi][ni][r] = 0.f;
#pragma unroll
    for (int kt = 0; kt < 2; ++kt) {
        int cb = kt * 64 + sg * 16;
        bf16x8 a0 = *(const bf16x8*)&Ct[swz(R * 32 + rr, cb)];
        bf16x8 a1 = *(const bf16x8*)&Ct[swz(R * 32 + 16 + rr, cb)];
        bf16x8 b0 = *(const bf16x8*)&Bt[swz(Cq * 32 + rr, cb)];
        bf16x8 b1 = *(const bf16x8*)&Bt[swz(Cq * 32 + 16 + rr, cb)];
        g[0][0] = __builtin_amdgcn_mfma_f32_16x16x32_bf16(a0, b0, g[0][0], 0, 0, 0);
        g[0][1] = __builtin_amdgcn_mfma_f32_16x16x32_bf16(a0, b1, g[0][1], 0, 0, 0);
        g[1][0] = __builtin_amdgcn_mfma_f32_16x16x32_bf16(a1, b0, g[1][0], 0, 0, 0);
        g[1][1] = __builtin_amdgcn_mfma_f32_16x16x32_bf16(a1, b1, g[1][1], 0, 0, 0);
    }
#pragma unroll
    for (int mi = 0; mi < 2; ++mi)
#pragma unroll
        for (int ni = 0; ni < 2; ++ni)
#pragma unroll
            for (int r = 0; r < 4; ++r) {
                int i = R * 32 + mi * 16 + sg * 4 + r;
                int j = Cq * 32 + ni * 16 + rr;
                float v = (i >= j) ? g[mi][ni][r] * __expf(Sar[i] - Sar[j]) * dtvA[j] : 0.f;
                Gt[swz(i, j * 2)] = f2bf(v);
            }
    // B~T (LDS, transposed, scaled by wA)
#pragma unroll
    for (int half = 0; half < 2; ++half) {
        u16x8 bv = *(const u16x8*)&Bt[swz(row, q * 32 + half * 16)];
#pragma unroll
        for (int e = 0; e < 8; ++e)
            BTt[swz(q * 16 + half * 8 + e, row * 2)] = f2bf(bf2f(bv[e]) * wA[row]);
    }
    __syncthreads();

    f32x4 y[2][2], dh[2][2];
#pragma unroll
    for (int mi = 0; mi < 2; ++mi)
#pragma unroll
        for (int ni = 0; ni < 2; ++ni)
#pragma unroll
            for (int r = 0; r < 4; ++r) { y[mi][ni][r] = 0.f; dh[mi][ni][r] = 0.f; }
#pragma unroll
    for (int kt = 0; kt < 2; ++kt) {
        int cb = kt * 64 + sg * 16;
        bf16x8 xb0 = *(const bf16x8*)&XT[swz(Cq * 32 + rr, cb)];
        bf16x8 xb1 = *(const bf16x8*)&XT[swz(Cq * 32 + 16 + rr, cb)];
        bf16x8 ga0 = *(const bf16x8*)&Gt[swz(R * 32 + rr, cb)];
        bf16x8 ga1 = *(const bf16x8*)&Gt[swz(R * 32 + 16 + rr, cb)];
        bf16x8 ba0 = *(const bf16x8*)&BTt[swz(R * 32 + rr, cb)];
        bf16x8 ba1 = *(const bf16x8*)&BTt[swz(R * 32 + 16 + rr, cb)];
        y[0][0] = __builtin_amdgcn_mfma_f32_16x16x32_bf16(ga0, xb0, y[0][0], 0, 0, 0);
        y[0][1] = __builtin_amdgcn_mfma_f32_16x16x32_bf16(ga0, xb1, y[0][1], 0, 0, 0);
        y[1][0] = __builtin_amdgcn_mfma_f32_16x16x32_bf16(ga1, xb0, y[1][0], 0, 0, 0);
        y[1][1] = __builtin_amdgcn_mfma_f32_16x16x32_bf16(ga1, xb1, y[1][1], 0, 0, 0);
        dh[0][0] = __builtin_amdgcn_mfma_f32_16x16x32_bf16(ba0, xb0, dh[0][0], 0, 0, 0);
        dh[0][1] = __builtin_amdgcn_mfma_f32_16x16x32_bf16(ba0, xb1, dh[0][1], 0, 0, 0);
        dh[1][0] = __builtin_amdgcn_mfma_f32_16x16x32_bf16(ba1, xb0, dh[1][0], 0, 0, 0);
        dh[1][1] = __builtin_amdgcn_mfma_f32_16x16x32_bf16(ba1, xb1, dh[1][1], 0, 0, 0);
    }
#pragma unroll
    for (int mi = 0; mi < 2; ++mi)
#pragma unroll
        for (int ni = 0; ni < 2; ++ni)
#pragma unroll
            for (int r = 0; r < 4; ++r) {
                int i = R * 32 + mi * 16 + sg * 4 + r;
                int p = Cq * 32 + ni * 16 + rr;
                yi[(size_t)(t0g + i) * DIN + h * HDD + p] = f2bf(y[mi][ni][r]);
                DHb[(size_t)tau * 4096 + i * 64 + p] = f2bf(dh[mi][ni][r]);
            }
}

// ---------- SSD K2: sequential chunk-state carry ----------
__global__ __launch_bounds__(256) void ssd_carry(const u16* __restrict__ DHb,
                                                 const float* __restrict__ DC,
                                                 u16* __restrict__ HPREV) {
    int bid = blockIdx.x;
    int bh = bid >> 1, ph = bid & 1;
    int t = threadIdx.x;
    int s = t >> 2, p0 = ph * 32 + (t & 3) * 8;
    size_t base = (size_t)bh * NCHUNK * 4096 + s * 64 + p0;
    float Hv[8] = {0.f, 0.f, 0.f, 0.f, 0.f, 0.f, 0.f, 0.f};
    for (int c = 0; c < NCHUNK; ++c) {
        size_t off = base + (size_t)c * 4096;
        u16x8 hp;
#pragma unroll
        for (int e = 0; e < 8; ++e) hp[e] = f2bf(Hv[e]);
        *(u16x8*)&HPREV[off] = hp;
        float d = DC[bh * NCHUNK + c];
        u16x8 dv = *(const u16x8*)&DHb[off];
#pragma unroll
        for (int e = 0; e < 8; ++e) Hv[e] = d * Hv[e] + bf2f(dv[e]);
    }
}

// ---------- SSD K3: Y = Y_intra + (C·eS)·Hprev; fuse D·x, z-gate; emit per-tau y² partials ----------
__global__ __launch_bounds__(256) void ssd_final(const u16* __restrict__ Ccb,
                                                 const float* __restrict__ ESA,
                                                 const u16* __restrict__ HPREV,
                                                 const u16* __restrict__ xbc,
                                                 const u16* __restrict__ zx,
                                                 const float* __restrict__ Dp,
                                                 u16* __restrict__ yi,
                                                 float* __restrict__ PS) {
    __shared__ u16 C2t[4096], HT[4096];
    __shared__ float smem_ps[2][64];
    int tau = blockIdx.x;
    int b = tau >> 8, h = (tau >> 4) & 15, c = tau & 15;
    int t0g = b * LL + c * QCH;
    int t = threadIdx.x, lane = t & 63, wave = t >> 6;
    int row = t >> 2, q = t & 3;
    {
        float esa = ESA[(size_t)tau * 64 + row];
        const u16* cp = Ccb + (size_t)(t0g + row) * DST + q * 16;
#pragma unroll
        for (int half = 0; half < 2; ++half) {
            u16x8 cv = *(const u16x8*)(cp + half * 8);
            u16x8 oc;
#pragma unroll
            for (int e = 0; e < 8; ++e) oc[e] = f2bf(bf2f(cv[e]) * esa);
            *(u16x8*)&C2t[swz(row, q * 32 + half * 16)] = oc;
            u16x8 hv = *(const u16x8*)&HPREV[(size_t)tau * 4096 + row * 64 + q * 16 + half * 8];
#pragma unroll
            for (int e = 0; e < 8; ++e) HT[swz(q * 16 + half * 8 + e, row * 2)] = hv[e];
        }
    }
    __syncthreads();
    int R = wave >> 1, Cq = wave & 1, rr = lane & 15, sg = lane >> 4;
    float Dh = Dp[h];
    f32x4 acc[2][2];
#pragma unroll
    for (int mi = 0; mi < 2; ++mi)
#pragma unroll
        for (int ni = 0; ni < 2; ++ni)
#pragma unroll
            for (int r = 0; r < 4; ++r) {
                int i = R * 32 + mi * 16 + sg * 4 + r;
                int p = Cq * 32 + ni * 16 + rr;
                acc[mi][ni][r] = bf2f(yi[(size_t)(t0g + i) * DIN + h * HDD + p]);
            }
#pragma unroll
    for (int kt = 0; kt < 2; ++kt) {
        int cb = kt * 64 + sg * 16;
        bf16x8 a0 = *(const bf16x8*)&C2t[swz(R * 32 + rr, cb)];
        bf16x8 a1 = *(const bf16x8*)&C2t[swz(R * 32 + 16 + rr, cb)];
        bf16x8 b0 = *(const bf16x8*)&HT[swz(Cq * 32 + rr, cb)];
        bf16x8 b1 = *(const bf16x8*)&HT[swz(Cq * 32 + 16 + rr, cb)];
        acc[0][0] = __builtin_amdgcn_mfma_f32_16x16x32_bf16(a0, b0, acc[0][0], 0, 0, 0);
        acc[0][1] = __builtin_amdgcn_mfma_f32_16x16x32_bf16(a0, b1, acc[0][1], 0, 0, 0);
        acc[1][0] = __builtin_amdgcn_mfma_f32_16x16x32_bf16(a1, b0, acc[1][0], 0, 0, 0);
        acc[1][1] = __builtin_amdgcn_mfma_f32_16x16x32_bf16(a1, b1, acc[1][1], 0, 0, 0);
    }
    float ps[2][4];
#pragma unroll
    for (int mi = 0; mi < 2; ++mi)
#pragma unroll
        for (int r = 0; r < 4; ++r) ps[mi][r] = 0.f;
#pragma unroll
    for (int mi = 0; mi < 2; ++mi)
#pragma unroll
        for (int ni = 0; ni < 2; ++ni)
#pragma unroll
            for (int r = 0; r < 4; ++r) {
                int i = R * 32 + mi * 16 + sg * 4 + r;
                int p = Cq * 32 + ni * 16 + rr;
                size_t tok = t0g + i;
                int col = h * HDD + p;
                float xf = bf2f(xbc[tok * XBCS + col]);
                float zf = bf2f(zx[tok * NPADW + col]);
                float yo = (acc[mi][ni][r] + Dh * xf) * (zf / (1.f + __expf(-zf)));
                yi[tok * DIN + col] = f2bf(yo);
                ps[mi][r] += yo * yo;
            }
#pragma unroll
    for (int mi = 0; mi < 2; ++mi)
#pragma unroll
        for (int r = 0; r < 4; ++r) {
            float s2 = ps[mi][r];
            s2 += __shfl_xor(s2, 1, 64);
            s2 += __shfl_xor(s2, 2, 64);
            s2 += __shfl_xor(s2, 4, 64);
            s2 += __shfl_xor(s2, 8, 64);
            if (rr == 0) smem_ps[Cq][R * 32 + mi * 16 + sg * 4 + r] = s2;
        }
    __syncthreads();
    if (t < 64) PS[(size_t)tau * 64 + t] = smem_ps[0][t] + smem_ps[1][t];
}

extern "C" void kernel_launch(void* const* d_in, const int* in_sizes, int n_in,
                              void* d_out, int out_size, void* d_ws, size_t ws_size,
                              hipStream_t stream) {
    const float* x         = (const float*)d_in[0];
    const float* ln_w      = (const float*)d_in[1];
    const float* ln_b      = (const float*)d_in[2];
    const float* in_proj_w = (const float*)d_in[3];
    const float* conv1d_w  = (const float*)d_in[4];
    const float* conv1d_b  = (const float*)d_in[5];
    const float* dt_bias   = (const float*)d_in[6];
    const float* A_log     = (const float*)d_in[7];
    const float* Dp        = (const float*)d_in[8];
    const float* rms_w     = (const float*)d_in[9];
    const float* out_proj_w= (const float*)d_in[10];
    const float* conv2d_w  = (const float*)d_in[11];
    const float* conv2d_b  = (const float*)d_in[12];
    const float* bn_g      = (const float*)d_in[13];
    const float* bn_b      = (const float*)d_in[14];
    const float* bn_mean   = (const float*)d_in[15];
    const float* bn_var    = (const float*)d_in[16];

    const int TOK = NB * LL;  // 8192
    const int NTAU = NB * NHH * NCHUNK;  // 2048
    char* ws = (char*)d_ws;
    size_t off = 0;
    auto alloc = [&](size_t bytes) {
        void* p = ws + off;
        off += (bytes + 255) & ~(size_t)255;
        return p;
    };
    u16*   Win   = (u16*)alloc((size_t)NPADW * CIN * 2);
    u16*   WoutT = (u16*)alloc((size_t)DIN * CIN * 2);
    u16*   Wc2   = (u16*)alloc((size_t)CIN * CIN * 2);
    u16*   WCMB  = (u16*)alloc((size_t)CIN * DIN * 2);
    u16*   XN    = (u16*)alloc((size_t)TOK * CIN * 2);
    u16*   ZX    = (u16*)alloc((size_t)TOK * NPADW * 2);
    u16*   XBC   = (u16*)alloc((size_t)TOK * XBCS * 2);
    u16*   Bcb   = (u16*)alloc((size_t)TOK * DST * 2);
    u16*   Ccb   = (u16*)alloc((size_t)TOK * DST * 2);
    float2* DTDA = (float2*)alloc((size_t)TOK * NHH * 8);
    u16*   YI    = (u16*)alloc((size_t)TOK * DIN * 2);
    u16*   DHb   = (u16*)alloc((size_t)NTAU * 4096 * 2);
    u16*   HPREV = (u16*)alloc((size_t)NTAU * 4096 * 2);
    float* ESA   = (float*)alloc((size_t)NTAU * 64 * 4);
    float* PS    = (float*)alloc((size_t)NTAU * 64 * 4);
    float* DC    = (float*)alloc((size_t)NTAU * 4);
    float* BNSC  = (float*)alloc(CIN * 4);
    float* BNSH  = (float*)alloc(CIN * 4);

    // fused weight prep
    prep_all<<<PREP_WIN_BLKS + PREP_WC2_BLKS + 2, 256, 0, stream>>>(
        in_proj_w, Win, conv2d_w, Wc2, conv2d_b, bn_g, bn_b, bn_mean, bn_var, BNSC, BNSH);
    woutT_conv<<<128, 256, 0, stream>>>(out_proj_w, rms_w, WoutT);
    // W_comb[o][d] = sum_c Wc2[o][c] * WoutT[d][c]   (M=512, N=1024, K=512)
    gemm_bt<0><<<(CIN / 128) * (DIN / 64), 256, 0, stream>>>(Wc2, WoutT, WCMB, CIN, DIN, CIN, DIN,
                                                             DIN / 64, nullptr, nullptr, nullptr);

    ln_kernel<<<256, 256, 0, stream>>>(x, ln_w, ln_b, XN);

    // in_proj: only the NUSE=2176 consumed columns (z + xBC)
    gemm_bt<0><<<(TOK / 128) * (NUSE / 64), 256, 0, stream>>>(XN, Win, ZX, TOK, NUSE, CIN, NPADW,
                                                              NUSE / 64, nullptr, nullptr, nullptr);

    // fused conv1d + dt_gemv
    convdt<<<NB * (LL / CTT) + TOK / DTB, 288, 0, stream>>>(ZX, conv1d_w, conv1d_b, XBC, Bcb, Ccb,
                                                            XN, in_proj_w, dt_bias, A_log, DTDA);

    ssd_chunk<<<NTAU, 256, 0, stream>>>(Bcb, Ccb, XBC, DTDA, YI, DHb, ESA, DC);
    ssd_carry<<<256, 256, 0, stream>>>(DHb, DC, HPREV);
    ssd_final<<<NTAU, 256, 0, stream>>>(Ccb, ESA, HPREV, XBC, ZX, Dp, YI, PS);

    // fused out_proj + conv2d + BN + ReLU (per-token rms computed in-kernel from PS)
    gemm_bt<1><<<(CIN / 128) * (TOK / 64), 256, 0, stream>>>(WCMB, YI, d_out, CIN, TOK, DIN, 0,
                                                             TOK / 64, BNSC, BNSH, PS);
}

// Round 22
// 141.236 us; speedup vs baseline: 1.0507x; 1.0153x over previous
//
#include <hip/hip_runtime.h>
#include <hip/hip_bf16.h>

// Problem constants
#define NB 8
#define LL 1024        // H*W tokens per batch
#define CIN 512
#define DIN 1024       // d_inner
#define DXBC 1152      // d_inner + 2*d_state
#define DPROJ 2192     // actual in_proj rows
#define NPADW 2304     // ZX row stride (padded)
#define NUSE 2176      // cols of ZX actually consumed (z + xBC); 34 x 64
#define NHH 16
#define HDD 64
#define DST 64
#define NCHUNK 16
#define QCH 64         // chunk length
#define XBCS 1024      // XBC stored stride (x-part only)
#define CTT 8          // conv tokens per block
#define DTB 16         // dt tokens per block
#define NDT (NB * LL / DTB)   // 512 dt blocks (placed FIRST in the fused grid)

typedef unsigned short u16;
typedef unsigned int u32;
typedef __bf16 bf16x8 __attribute__((ext_vector_type(8)));
typedef float f32x4 __attribute__((ext_vector_type(4)));
typedef u16 u16x8 __attribute__((ext_vector_type(8)));

__device__ __forceinline__ float bf2f(u16 u) {
    u32 x = ((u32)u) << 16; float f; __builtin_memcpy(&f, &x, 4); return f;
}
__device__ __forceinline__ u16 f2bf(float f) {
    u32 x; __builtin_memcpy(&x, &f, 4);
    u32 r = x + 0x7fff + ((x >> 16) & 1);
    return (u16)(r >> 16);
}

__device__ __forceinline__ void gload16(const u16* g, u16* l) {
    __builtin_amdgcn_global_load_lds((__attribute__((address_space(1))) void*)(g),
                                     (__attribute__((address_space(3))) void*)(l), 16, 0, 0);
}

// swizzled u16 index into a [64][64] bf16 LDS tile (128B rows, 16B-slot XOR swizzle)
__device__ __forceinline__ int swz(int row, int cb) {
    return row * 64 + ((cb ^ ((row & 7) << 4)) >> 1);
}

// ---------- fused weight prep: Win pad-convert | Wc2 convert | BN prep ----------
#define PREP_WIN_BLKS 4608   // NPADW*CIN/256
#define PREP_WC2_BLKS 1024   // CIN*CIN/256
__global__ __launch_bounds__(256) void prep_all(const float* __restrict__ ipw, u16* __restrict__ Win,
                                                const float* __restrict__ c2w, u16* __restrict__ Wc2,
                                                const float* __restrict__ cb, const float* __restrict__ g,
                                                const float* __restrict__ bb, const float* __restrict__ mean,
                                                const float* __restrict__ var,
                                                float* __restrict__ scale, float* __restrict__ shift) {
    int bid = blockIdx.x;
    if (bid < PREP_WIN_BLKS) {
        int i = bid * 256 + threadIdx.x;
        Win[i] = (i < DPROJ * CIN) ? f2bf(ipw[i]) : (u16)0;
    } else if (bid < PREP_WIN_BLKS + PREP_WC2_BLKS) {
        int i = (bid - PREP_WIN_BLKS) * 256 + threadIdx.x;
        Wc2[i] = f2bf(c2w[i]);
    } else {
        int i = (bid - PREP_WIN_BLKS - PREP_WC2_BLKS) * 256 + threadIdx.x;
        if (i < CIN) {
            float rs = rsqrtf(var[i] + 1e-5f);
            float sc = g[i] * rs;
            scale[i] = sc;
            shift[i] = (cb[i] - mean[i]) * sc + bb[i];
        }
    }
}

// WoutT[d][c] = out_proj_w[c][d] * rms_w[d]   (LDS-tiled transpose, 64x64 tiles)
__global__ __launch_bounds__(256) void woutT_conv(const float* __restrict__ s,
                                                  const float* __restrict__ rw,
                                                  u16* __restrict__ dt) {
    __shared__ float tile[64][65];
    int bc = blockIdx.x & 7, bd = blockIdx.x >> 3;
    int c0 = bc * 64, d0 = bd * 64;
    int t = threadIdx.x;
    int r4 = t >> 6, cc = t & 63;
#pragma unroll
    for (int rr = 0; rr < 16; ++rr) {
        int row = r4 * 16 + rr;
        tile[row][cc] = s[(size_t)(c0 + row) * DIN + d0 + cc];
    }
    __syncthreads();
#pragma unroll
    for (int rr = 0; rr < 16; ++rr) {
        int row = r4 * 16 + rr;
        dt[(size_t)(d0 + row) * CIN + c0 + cc] = f2bf(tile[cc][row] * rw[d0 + row]);
    }
}

// ---------- LayerNorm over channels + transpose (B,C,HW) -> (tok, C) bf16 ----------
__global__ __launch_bounds__(256) void ln_kernel(const float* __restrict__ x,
                                                 const float* __restrict__ lw,
                                                 const float* __restrict__ lb,
                                                 u16* __restrict__ xn) {
    __shared__ u16 tile[CIN * 33];
    __shared__ float psum[8][32], psq[8][32], muA[32], rsA[32];
    int bid = blockIdx.x;
    int b = bid >> 5, hw0 = (bid & 31) * 32;
    int t = threadIdx.x;
    int hw = t & 31, cg = t >> 5;
    const float* xb = x + (size_t)b * CIN * LL + hw0 + hw;
    float s = 0.f, sq = 0.f;
    for (int r = 0; r < CIN / 8; ++r) {
        int c = r * 8 + cg;
        float v = xb[(size_t)c * LL];
        s += v; sq += v * v;
        tile[c * 33 + hw] = f2bf(v);
    }
    psum[cg][hw] = s; psq[cg][hw] = sq;
    __syncthreads();
    if (t < 32) {
        float ss = 0.f, qq = 0.f;
        for (int g = 0; g < 8; ++g) { ss += psum[g][t]; qq += psq[g][t]; }
        float mu = ss * (1.f / CIN);
        float var = qq * (1.f / CIN) - mu * mu;
        muA[t] = mu; rsA[t] = rsqrtf(var + 1e-5f);
    }
    __syncthreads();
    for (int r = 0; r < 64; ++r) {
        int idx = r * 256 + t;
        int c = idx & (CIN - 1);
        int hh = idx >> 9;
        float v = (bf2f(tile[c * 33 + hh]) - muA[hh]) * rsA[hh] * lw[c] + lb[c];
        xn[((size_t)(b * LL + hw0 + hh)) * CIN + c] = f2bf(v);
    }
}

// ---------- bf16 MFMA GEMM: 128x64 tile, BK=64, XOR-swizzled LDS, 2-phase counted vmcnt ----------
// EPI 0: bf16 store row-major ldc.
// EPI 1: v*rs(col from PS) -> BN(scale/shift[row]) -> ReLU -> remapped f32 store (d_out layout).
template <int EPI>
__global__ __launch_bounds__(256) void gemm_bt(const u16* __restrict__ A, const u16* __restrict__ Bw,
                                               void* __restrict__ Cout, int M, int N, int K, int ldc,
                                               int nx,
                                               const float* __restrict__ scale,
                                               const float* __restrict__ shift,
                                               const float* __restrict__ PS) {
    __shared__ u16 As[2][128 * 64], Bs[2][64 * 64];
    __shared__ float rsl[64];
    int t = threadIdx.x;
    int lane = t & 63, wave = t >> 6;
    // bijective XCD swizzle (m204)
    int nblk = gridDim.x;
    int qq = nblk >> 3, rm = nblk & 7;
    int xcd = blockIdx.x & 7, idx = blockIdx.x >> 3;
    int swzb = (xcd < rm ? xcd * (qq + 1) : rm * (qq + 1) + (xcd - rm) * qq) + idx;
    int m0 = (swzb / nx) * 128, n0 = (swzb % nx) * 64;
    int wr = wave >> 1, wc = wave & 1;
    f32x4 acc[4][2];
    for (int m = 0; m < 4; ++m)
        for (int n = 0; n < 2; ++n)
            for (int q = 0; q < 4; ++q) acc[m][n][q] = 0.f;

    if (EPI == 1) {
        // per-token rms scale for this block's 64 token-columns
        if (t < 64) {
            int tok = n0 + t;
            int b = tok >> 10, rem = tok & 1023;
            int c = rem >> 6, ii = rem & 63;
            float s = 0.f;
#pragma unroll
            for (int h = 0; h < NHH; ++h)
                s += PS[(size_t)(((b << 4) + h) * 16 + c) * 64 + ii];
            rsl[t] = rsqrtf(s * (1.f / DIN) + 1e-5f);
        }
        __syncthreads();
    }

    const u16* Arow = A + (size_t)m0 * K;
    const u16* Brow = Bw + (size_t)n0 * K;
    int s4 = lane >> 4;
    int rr = lane & 15;

    auto STAGE = [&](int buf, int k0) {
#pragma unroll
        for (int j = 0; j < 4; ++j) {
            int e = j * 256 + t;          // A: 1024 16B-slots, 8 per row
            int r = e >> 3, sr = e & 7;
            int src = (sr ^ (r & 7)) * 8;
            gload16(Arow + (size_t)r * K + k0 + src, &As[buf][e * 8]);
        }
#pragma unroll
        for (int j = 0; j < 2; ++j) {
            int e = j * 256 + t;          // B: 512 16B-slots
            int r = e >> 3, sr = e & 7;
            int src = (sr ^ (r & 7)) * 8;
            gload16(Brow + (size_t)r * K + k0 + src, &Bs[buf][e * 8]);
        }
    };

    STAGE(0, 0);                       // 6 loads/thread in flight
    int NK = K >> 6, cur = 0;
    for (int kt = 0; kt < NK; ++kt) {
        if (kt + 1 < NK) {
            STAGE(cur ^ 1, (kt + 1) << 6);             // +6 loads (next tile)
            asm volatile("s_waitcnt vmcnt(6)" ::: "memory");  // cur tile's 6 done; next 6 fly
        } else {
            asm volatile("s_waitcnt vmcnt(0)" ::: "memory");
        }
        __builtin_amdgcn_s_barrier();   // all waves' cur-tile loads landed
        __builtin_amdgcn_sched_barrier(0);
#pragma unroll
        for (int kk = 0; kk < 2; ++kk) {
            bf16x8 af[4], bfr[2];
#pragma unroll
            for (int m = 0; m < 4; ++m) {
                int row = wr * 64 + m * 16 + rr;
                int ss = (kk * 4 + s4) ^ (row & 7);
                af[m] = *(const bf16x8*)&As[cur][row * 64 + ss * 8];
            }
#pragma unroll
            for (int n = 0; n < 2; ++n) {
                int row = wc * 32 + n * 16 + rr;
                int ss = (kk * 4 + s4) ^ (row & 7);
                bfr[n] = *(const bf16x8*)&Bs[cur][row * 64 + ss * 8];
            }
#pragma unroll
            for (int m = 0; m < 4; ++m)
#pragma unroll
                for (int n = 0; n < 2; ++n)
                    acc[m][n] = __builtin_amdgcn_mfma_f32_16x16x32_bf16(af[m], bfr[n], acc[m][n], 0, 0, 0);
        }
        __builtin_amdgcn_s_barrier();   // protect buf[cur] before next iter's STAGE overwrites it
        cur ^= 1;
    }
    int fq = lane >> 4, fr = lane & 15;
#pragma unroll
    for (int m = 0; m < 4; ++m) {
#pragma unroll
        for (int n = 0; n < 2; ++n) {
            int col = n0 + wc * 32 + n * 16 + fr;
#pragma unroll
            for (int q = 0; q < 4; ++q) {
                int row = m0 + wr * 64 + m * 16 + fq * 4 + q;
                float v = acc[m][n][q];
                if (EPI == 0) {
                    ((u16*)Cout)[(size_t)row * ldc + col] = f2bf(v);
                } else {
                    v = v * rsl[col - n0];
                    v = v * scale[row] + shift[row];
                    v = v > 0.f ? v : 0.f;
                    // row = out-channel o, col = token (b*1024+hw)
                    ((float*)Cout)[((size_t)(col >> 10)) * (CIN * LL) + (size_t)row * LL + (col & 1023)] = v;
                }
            }
        }
    }
}

// ---------- fused: dt GEMV (blocks 0..511) | depthwise conv1d+SiLU (blocks 512..1535) ----------
__global__ __launch_bounds__(288) void convdt(const u16* __restrict__ zx,
                                              const float* __restrict__ w,
                                              const float* __restrict__ bias,
                                              u16* __restrict__ xbc,
                                              u16* __restrict__ Bc, u16* __restrict__ Cc,
                                              const u16* __restrict__ xn,
                                              const float* __restrict__ wproj,
                                              const float* __restrict__ dt_bias,
                                              const float* __restrict__ A_log,
                                              float2* __restrict__ dtda) {
    int bid = blockIdx.x;
    int t = threadIdx.x;
    if (bid >= NDT) {
        // ---- conv branch (identical arithmetic to R14) ----
        int cb = bid - NDT;
        int b = cb >> 7;
        int l0 = (cb & 127) * CTT;
        bool isX = t < 256;
        int ch = isX ? t * 4 : 1024 + (t - 256) * 4;

        float4 wv0 = *(const float4*)&w[(ch + 0) * 4];
        float4 wv1 = *(const float4*)&w[(ch + 1) * 4];
        float4 wv2 = *(const float4*)&w[(ch + 2) * 4];
        float4 wv3 = *(const float4*)&w[(ch + 3) * 4];
        float4 bv = *(const float4*)&bias[ch];

        ushort4 xin[CTT + 3];
        const u16* src = zx + (size_t)(b * LL + l0 - 3) * NPADW + DIN + ch;
#pragma unroll
        for (int i = 0; i < CTT + 3; ++i) {
            ushort4 v = {0, 0, 0, 0};
            if (l0 + i - 3 >= 0) v = *(const ushort4*)(src + (size_t)i * NPADW);
            xin[i] = v;
        }
#pragma unroll
        for (int i = 0; i < CTT; ++i) {
            int tok = b * LL + l0 + i;
            float a0 = bv.x + bf2f(xin[i].x) * wv0.x + bf2f(xin[i + 1].x) * wv0.y +
                       bf2f(xin[i + 2].x) * wv0.z + bf2f(xin[i + 3].x) * wv0.w;
            float a1 = bv.y + bf2f(xin[i].y) * wv1.x + bf2f(xin[i + 1].y) * wv1.y +
                       bf2f(xin[i + 2].y) * wv1.z + bf2f(xin[i + 3].y) * wv1.w;
            float a2 = bv.z + bf2f(xin[i].z) * wv2.x + bf2f(xin[i + 1].z) * wv2.y +
                       bf2f(xin[i + 2].z) * wv2.z + bf2f(xin[i + 3].z) * wv2.w;
            float a3 = bv.w + bf2f(xin[i].w) * wv3.x + bf2f(xin[i + 1].w) * wv3.y +
                       bf2f(xin[i + 2].w) * wv3.z + bf2f(xin[i + 3].w) * wv3.w;
            float s0 = a0 / (1.f + __expf(-a0));
            float s1 = a1 / (1.f + __expf(-a1));
            float s2 = a2 / (1.f + __expf(-a2));
            float s3 = a3 / (1.f + __expf(-a3));
            ushort4 o;
            o.x = f2bf(s0); o.y = f2bf(s1); o.z = f2bf(s2); o.w = f2bf(s3);
            if (isX) {
                *(ushort4*)&xbc[(size_t)tok * XBCS + ch] = o;
            } else {
                int s = ch - 1024;
                if (s < DST) *(ushort4*)&Bc[(size_t)tok * DST + s] = o;
                else         *(ushort4*)&Cc[(size_t)tok * DST + (s - DST)] = o;
            }
        }
    } else {
        // ---- dt branch (256 active threads) ----
        if (t >= 256) return;
        int h = t >> 4, part = t & 15;
        int tok0 = bid * DTB;
        const float* wr = wproj + (size_t)(DIN + DXBC + h) * CIN + part * 32;
        float4 wv[8];
#pragma unroll
        for (int i = 0; i < 8; ++i) wv[i] = *(const float4*)&wr[i * 4];
        const float* wf = (const float*)wv;
        float dtb = dt_bias[h];
        float An = -__expf(A_log[h]);
#pragma unroll
        for (int tl = 0; tl < DTB; ++tl) {
            int tok = tok0 + tl;
            const u16* xr = xn + (size_t)tok * CIN + part * 32;
            u16x8 xv0 = *(const u16x8*)&xr[0];
            u16x8 xv1 = *(const u16x8*)&xr[8];
            u16x8 xv2 = *(const u16x8*)&xr[16];
            u16x8 xv3 = *(const u16x8*)&xr[24];
            float s = 0.f;
#pragma unroll
            for (int i = 0; i < 8; ++i) s += bf2f(xv0[i]) * wf[i];
#pragma unroll
            for (int i = 0; i < 8; ++i) s += bf2f(xv1[i]) * wf[8 + i];
#pragma unroll
            for (int i = 0; i < 8; ++i) s += bf2f(xv2[i]) * wf[16 + i];
#pragma unroll
            for (int i = 0; i < 8; ++i) s += bf2f(xv3[i]) * wf[24 + i];
            s += __shfl_xor(s, 1, 64);
            s += __shfl_xor(s, 2, 64);
            s += __shfl_xor(s, 4, 64);
            s += __shfl_xor(s, 8, 64);
            if (part == 0) {
                float si = s + dtb;
                float dtv = si > 15.f ? si : __logf(1.f + __expf(si));
                float2 dd; dd.x = dtv; dd.y = dtv * An;
                dtda[(size_t)tok * NHH + h] = dd;
            }
        }
    }
}

// ---------- SSD K1: G̃, Y_intra(bf16), ΔH(bf16), ESA, d_c ----------
__global__ __launch_bounds__(256) void ssd_chunk(const u16* __restrict__ Bcb,
                                                 const u16* __restrict__ Ccb,
                                                 const u16* __restrict__ xbc,
                                                 const float2* __restrict__ dtda,
                                                 u16* __restrict__ yi,
                                                 u16* __restrict__ DHb,
                                                 float* __restrict__ ESA,
                                                 float* __restrict__ DC) {
    __shared__ u16 Bt[4096], Ct[4096], XT[4096], BTt[4096], Gt[4096];
    __shared__ float Sar[64], dtvA[64], wA[64];
    int tau = blockIdx.x;
    int b = tau >> 8, h = (tau >> 4) & 15, c = tau & 15;
    int t0g = b * LL + c * QCH;
    int t = threadIdx.x, lane = t & 63, wave = t >> 6;
    int row = t >> 2, q = t & 3;

    {
        const u16* bp = Bcb + (size_t)(t0g + row) * DST + q * 16;
        const u16* cp = Ccb + (size_t)(t0g + row) * DST + q * 16;
        u16x8 b0v = *(const u16x8*)bp;
        u16x8 b1v = *(const u16x8*)(bp + 8);
        *(u16x8*)&Bt[swz(row, q * 32)] = b0v;
        *(u16x8*)&Bt[swz(row, q * 32 + 16)] = b1v;
        u16x8 c0v = *(const u16x8*)cp;
        u16x8 c1v = *(const u16x8*)(cp + 8);
        *(u16x8*)&Ct[swz(row, q * 32)] = c0v;
        *(u16x8*)&Ct[swz(row, q * 32 + 16)] = c1v;
        const u16* xp = xbc + (size_t)(t0g + row) * XBCS + h * HDD + q * 16;
        u16x8 x0 = *(const u16x8*)xp;
        u16x8 x1 = *(const u16x8*)(xp + 8);
#pragma unroll
        for (int e = 0; e < 8; ++e) XT[swz(q * 16 + e, row * 2)] = x0[e];
#pragma unroll
        for (int e = 0; e < 8; ++e) XT[swz(q * 16 + 8 + e, row * 2)] = x1[e];
    }
    if (t < 64) {
        float2 dd = dtda[(size_t)(t0g + t) * NHH + h];
        float s = dd.y;
#pragma unroll
        for (int off = 1; off < 64; off <<= 1) {
            float u = __shfl_up(s, off, 64);
            if (t >= off) s += u;
        }
        float SQ = __shfl(s, 63, 64);
        Sar[t] = s; dtvA[t] = dd.x;
        wA[t] = __expf(SQ - s) * dd.x;
        ESA[(size_t)tau * 64 + t] = __expf(s);
        if (t == 0) DC[tau] = __expf(SQ);
    }
    __syncthreads();

    int R = wave >> 1, Cq = wave & 1, rr = lane & 15, sg = lane >> 4;
    f32x4 g[2][2];
#pragma unroll
    for (int mi = 0; mi < 2; ++mi)
#pragma unroll
        for (int ni = 0; ni < 2; ++ni)
#pragma unroll
            for (int r = 0; r < 4; ++r) g[mi][ni][r] = 0.f;
#pragma unroll
    for (int kt = 0; kt < 2; ++kt) {
        int cb = kt * 64 + sg * 16;
        bf16x8 a0 = *(const bf16x8*)&Ct[swz(R * 32 + rr, cb)];
        bf16x8 a1 = *(const bf16x8*)&Ct[swz(R * 32 + 16 + rr, cb)];
        bf16x8 b0 = *(const bf16x8*)&Bt[swz(Cq * 32 + rr, cb)];
        bf16x8 b1 = *(const bf16x8*)&Bt[swz(Cq * 32 + 16 + rr, cb)];
        g[0][0] = __builtin_amdgcn_mfma_f32_16x16x32_bf16(a0, b0, g[0][0], 0, 0, 0);
        g[0][1] = __builtin_amdgcn_mfma_f32_16x16x32_bf16(a0, b1, g[0][1], 0, 0, 0);
        g[1][0] = __builtin_amdgcn_mfma_f32_16x16x32_bf16(a1, b0, g[1][0], 0, 0, 0);
        g[1][1] = __builtin_amdgcn_mfma_f32_16x16x32_bf16(a1, b1, g[1][1], 0, 0, 0);
    }
#pragma unroll
    for (int mi = 0; mi < 2; ++mi)
#pragma unroll
        for (int ni = 0; ni < 2; ++ni)
#pragma unroll
            for (int r = 0; r < 4; ++r) {
                int i = R * 32 + mi * 16 + sg * 4 + r;
                int j = Cq * 32 + ni * 16 + rr;
                float v = (i >= j) ? g[mi][ni][r] * __expf(Sar[i] - Sar[j]) * dtvA[j] : 0.f;
                Gt[swz(i, j * 2)] = f2bf(v);
            }
    // B~T (LDS, transposed, scaled by wA)
#pragma unroll
    for (int half = 0; half < 2; ++half) {
        u16x8 bv = *(const u16x8*)&Bt[swz(row, q * 32 + half * 16)];
#pragma unroll
        for (int e = 0; e < 8; ++e)
            BTt[swz(q * 16 + half * 8 + e, row * 2)] = f2bf(bf2f(bv[e]) * wA[row]);
    }
    __syncthreads();

    f32x4 y[2][2], dh[2][2];
#pragma unroll
    for (int mi = 0; mi < 2; ++mi)
#pragma unroll
        for (int ni = 0; ni < 2; ++ni)
#pragma unroll
            for (int r = 0; r < 4; ++r) { y[mi][ni][r] = 0.f; dh[mi][ni][r] = 0.f; }
#pragma unroll
    for (int kt = 0; kt < 2; ++kt) {
        int cb = kt * 64 + sg * 16;
        bf16x8 xb0 = *(const bf16x8*)&XT[swz(Cq * 32 + rr, cb)];
        bf16x8 xb1 = *(const bf16x8*)&XT[swz(Cq * 32 + 16 + rr, cb)];
        bf16x8 ga0 = *(const bf16x8*)&Gt[swz(R * 32 + rr, cb)];
        bf16x8 ga1 = *(const bf16x8*)&Gt[swz(R * 32 + 16 + rr, cb)];
        bf16x8 ba0 = *(const bf16x8*)&BTt[swz(R * 32 + rr, cb)];
        bf16x8 ba1 = *(const bf16x8*)&BTt[swz(R * 32 + 16 + rr, cb)];
        y[0][0] = __builtin_amdgcn_mfma_f32_16x16x32_bf16(ga0, xb0, y[0][0], 0, 0, 0);
        y[0][1] = __builtin_amdgcn_mfma_f32_16x16x32_bf16(ga0, xb1, y[0][1], 0, 0, 0);
        y[1][0] = __builtin_amdgcn_mfma_f32_16x16x32_bf16(ga1, xb0, y[1][0], 0, 0, 0);
        y[1][1] = __builtin_amdgcn_mfma_f32_16x16x32_bf16(ga1, xb1, y[1][1], 0, 0, 0);
        dh[0][0] = __builtin_amdgcn_mfma_f32_16x16x32_bf16(ba0, xb0, dh[0][0], 0, 0, 0);
        dh[0][1] = __builtin_amdgcn_mfma_f32_16x16x32_bf16(ba0, xb1, dh[0][1], 0, 0, 0);
        dh[1][0] = __builtin_amdgcn_mfma_f32_16x16x32_bf16(ba1, xb0, dh[1][0], 0, 0, 0);
        dh[1][1] = __builtin_amdgcn_mfma_f32_16x16x32_bf16(ba1, xb1, dh[1][1], 0, 0, 0);
    }
#pragma unroll
    for (int mi = 0; mi < 2; ++mi)
#pragma unroll
        for (int ni = 0; ni < 2; ++ni)
#pragma unroll
            for (int r = 0; r < 4; ++r) {
                int i = R * 32 + mi * 16 + sg * 4 + r;
                int p = Cq * 32 + ni * 16 + rr;
                yi[(size_t)(t0g + i) * DIN + h * HDD + p] = f2bf(y[mi][ni][r]);
                DHb[(size_t)tau * 4096 + i * 64 + p] = f2bf(dh[mi][ni][r]);
            }
}

// ---------- SSD K2: sequential chunk-state carry ----------
__global__ __launch_bounds__(256) void ssd_carry(const u16* __restrict__ DHb,
                                                 const float* __restrict__ DC,
                                                 u16* __restrict__ HPREV) {
    int bid = blockIdx.x;
    int bh = bid >> 1, ph = bid & 1;
    int t = threadIdx.x;
    int s = t >> 2, p0 = ph * 32 + (t & 3) * 8;
    size_t base = (size_t)bh * NCHUNK * 4096 + s * 64 + p0;
    float Hv[8] = {0.f, 0.f, 0.f, 0.f, 0.f, 0.f, 0.f, 0.f};
    for (int c = 0; c < NCHUNK; ++c) {
        size_t off = base + (size_t)c * 4096;
        u16x8 hp;
#pragma unroll
        for (int e = 0; e < 8; ++e) hp[e] = f2bf(Hv[e]);
        *(u16x8*)&HPREV[off] = hp;
        float d = DC[bh * NCHUNK + c];
        u16x8 dv = *(const u16x8*)&DHb[off];
#pragma unroll
        for (int e = 0; e < 8; ++e) Hv[e] = d * Hv[e] + bf2f(dv[e]);
    }
}

// ---------- SSD K3: Y = Y_intra + (C·eS)·Hprev; fuse D·x, z-gate; emit per-tau y² partials ----------
__global__ __launch_bounds__(256) void ssd_final(const u16* __restrict__ Ccb,
                                                 const float* __restrict__ ESA,
                                                 const u16* __restrict__ HPREV,
                                                 const u16* __restrict__ xbc,
                                                 const u16* __restrict__ zx,
                                                 const float* __restrict__ Dp,
                                                 u16* __restrict__ yi,
                                                 float* __restrict__ PS) {
    __shared__ u16 C2t[4096], HT[4096];
    __shared__ float smem_ps[2][64];
    int tau = blockIdx.x;
    int b = tau >> 8, h = (tau >> 4) & 15, c = tau & 15;
    int t0g = b * LL + c * QCH;
    int t = threadIdx.x, lane = t & 63, wave = t >> 6;
    int row = t >> 2, q = t & 3;
    {
        float esa = ESA[(size_t)tau * 64 + row];
        const u16* cp = Ccb + (size_t)(t0g + row) * DST + q * 16;
#pragma unroll
        for (int half = 0; half < 2; ++half) {
            u16x8 cv = *(const u16x8*)(cp + half * 8);
            u16x8 oc;
#pragma unroll
            for (int e = 0; e < 8; ++e) oc[e] = f2bf(bf2f(cv[e]) * esa);
            *(u16x8*)&C2t[swz(row, q * 32 + half * 16)] = oc;
            u16x8 hv = *(const u16x8*)&HPREV[(size_t)tau * 4096 + row * 64 + q * 16 + half * 8];
#pragma unroll
            for (int e = 0; e < 8; ++e) HT[swz(q * 16 + half * 8 + e, row * 2)] = hv[e];
        }
    }
    __syncthreads();
    int R = wave >> 1, Cq = wave & 1, rr = lane & 15, sg = lane >> 4;
    float Dh = Dp[h];
    f32x4 acc[2][2];
#pragma unroll
    for (int mi = 0; mi < 2; ++mi)
#pragma unroll
        for (int ni = 0; ni < 2; ++ni)
#pragma unroll
            for (int r = 0; r < 4; ++r) {
                int i = R * 32 + mi * 16 + sg * 4 + r;
                int p = Cq * 32 + ni * 16 + rr;
                acc[mi][ni][r] = bf2f(yi[(size_t)(t0g + i) * DIN + h * HDD + p]);
            }
#pragma unroll
    for (int kt = 0; kt < 2; ++kt) {
        int cb = kt * 64 + sg * 16;
        bf16x8 a0 = *(const bf16x8*)&C2t[swz(R * 32 + rr, cb)];
        bf16x8 a1 = *(const bf16x8*)&C2t[swz(R * 32 + 16 + rr, cb)];
        bf16x8 b0 = *(const bf16x8*)&HT[swz(Cq * 32 + rr, cb)];
        bf16x8 b1 = *(const bf16x8*)&HT[swz(Cq * 32 + 16 + rr, cb)];
        acc[0][0] = __builtin_amdgcn_mfma_f32_16x16x32_bf16(a0, b0, acc[0][0], 0, 0, 0);
        acc[0][1] = __builtin_amdgcn_mfma_f32_16x16x32_bf16(a0, b1, acc[0][1], 0, 0, 0);
        acc[1][0] = __builtin_amdgcn_mfma_f32_16x16x32_bf16(a1, b0, acc[1][0], 0, 0, 0);
        acc[1][1] = __builtin_amdgcn_mfma_f32_16x16x32_bf16(a1, b1, acc[1][1], 0, 0, 0);
    }
    float ps[2][4];
#pragma unroll
    for (int mi = 0; mi < 2; ++mi)
#pragma unroll
        for (int r = 0; r < 4; ++r) ps[mi][r] = 0.f;
#pragma unroll
    for (int mi = 0; mi < 2; ++mi)
#pragma unroll
        for (int ni = 0; ni < 2; ++ni)
#pragma unroll
            for (int r = 0; r < 4; ++r) {
                int i = R * 32 + mi * 16 + sg * 4 + r;
                int p = Cq * 32 + ni * 16 + rr;
                size_t tok = t0g + i;
                int col = h * HDD + p;
                float xf = bf2f(xbc[tok * XBCS + col]);
                float zf = bf2f(zx[tok * NPADW + col]);
                float yo = (acc[mi][ni][r] + Dh * xf) * (zf / (1.f + __expf(-zf)));
                yi[tok * DIN + col] = f2bf(yo);
                ps[mi][r] += yo * yo;
            }
#pragma unroll
    for (int mi = 0; mi < 2; ++mi)
#pragma unroll
        for (int r = 0; r < 4; ++r) {
            float s2 = ps[mi][r];
            s2 += __shfl_xor(s2, 1, 64);
            s2 += __shfl_xor(s2, 2, 64);
            s2 += __shfl_xor(s2, 4, 64);
            s2 += __shfl_xor(s2, 8, 64);
            if (rr == 0) smem_ps[Cq][R * 32 + mi * 16 + sg * 4 + r] = s2;
        }
    __syncthreads();
    if (t < 64) PS[(size_t)tau * 64 + t] = smem_ps[0][t] + smem_ps[1][t];
}

extern "C" void kernel_launch(void* const* d_in, const int* in_sizes, int n_in,
                              void* d_out, int out_size, void* d_ws, size_t ws_size,
                              hipStream_t stream) {
    const float* x         = (const float*)d_in[0];
    const float* ln_w      = (const float*)d_in[1];
    const float* ln_b      = (const float*)d_in[2];
    const float* in_proj_w = (const float*)d_in[3];
    const float* conv1d_w  = (const float*)d_in[4];
    const float* conv1d_b  = (const float*)d_in[5];
    const float* dt_bias   = (const float*)d_in[6];
    const float* A_log     = (const float*)d_in[7];
    const float* Dp        = (const float*)d_in[8];
    const float* rms_w     = (const float*)d_in[9];
    const float* out_proj_w= (const float*)d_in[10];
    const float* conv2d_w  = (const float*)d_in[11];
    const float* conv2d_b  = (const float*)d_in[12];
    const float* bn_g      = (const float*)d_in[13];
    const float* bn_b      = (const float*)d_in[14];
    const float* bn_mean   = (const float*)d_in[15];
    const float* bn_var    = (const float*)d_in[16];

    const int TOK = NB * LL;  // 8192
    const int NTAU = NB * NHH * NCHUNK;  // 2048
    char* ws = (char*)d_ws;
    size_t off = 0;
    auto alloc = [&](size_t bytes) {
        void* p = ws + off;
        off += (bytes + 255) & ~(size_t)255;
        return p;
    };
    u16*   Win   = (u16*)alloc((size_t)NPADW * CIN * 2);
    u16*   WoutT = (u16*)alloc((size_t)DIN * CIN * 2);
    u16*   Wc2   = (u16*)alloc((size_t)CIN * CIN * 2);
    u16*   WCMB  = (u16*)alloc((size_t)CIN * DIN * 2);
    u16*   XN    = (u16*)alloc((size_t)TOK * CIN * 2);
    u16*   ZX    = (u16*)alloc((size_t)TOK * NPADW * 2);
    u16*   XBC   = (u16*)alloc((size_t)TOK * XBCS * 2);
    u16*   Bcb   = (u16*)alloc((size_t)TOK * DST * 2);
    u16*   Ccb   = (u16*)alloc((size_t)TOK * DST * 2);
    float2* DTDA = (float2*)alloc((size_t)TOK * NHH * 8);
    u16*   YI    = (u16*)alloc((size_t)TOK * DIN * 2);
    u16*   DHb   = (u16*)alloc((size_t)NTAU * 4096 * 2);
    u16*   HPREV = (u16*)alloc((size_t)NTAU * 4096 * 2);
    float* ESA   = (float*)alloc((size_t)NTAU * 64 * 4);
    float* PS    = (float*)alloc((size_t)NTAU * 64 * 4);
    float* DC    = (float*)alloc((size_t)NTAU * 4);
    float* BNSC  = (float*)alloc(CIN * 4);
    float* BNSH  = (float*)alloc(CIN * 4);

    // fused weight prep
    prep_all<<<PREP_WIN_BLKS + PREP_WC2_BLKS + 2, 256, 0, stream>>>(
        in_proj_w, Win, conv2d_w, Wc2, conv2d_b, bn_g, bn_b, bn_mean, bn_var, BNSC, BNSH);
    woutT_conv<<<128, 256, 0, stream>>>(out_proj_w, rms_w, WoutT);
    // W_comb[o][d] = sum_c Wc2[o][c] * WoutT[d][c]   (M=512, N=1024, K=512)
    gemm_bt<0><<<(CIN / 128) * (DIN / 64), 256, 0, stream>>>(Wc2, WoutT, WCMB, CIN, DIN, CIN, DIN,
                                                             DIN / 64, nullptr, nullptr, nullptr);

    ln_kernel<<<256, 256, 0, stream>>>(x, ln_w, ln_b, XN);

    // in_proj: only the NUSE=2176 consumed columns (z + xBC)
    gemm_bt<0><<<(TOK / 128) * (NUSE / 64), 256, 0, stream>>>(XN, Win, ZX, TOK, NUSE, CIN, NPADW,
                                                              NUSE / 64, nullptr, nullptr, nullptr);

    // fused dt (first) + conv1d
    convdt<<<NDT + NB * (LL / CTT), 288, 0, stream>>>(ZX, conv1d_w, conv1d_b, XBC, Bcb, Ccb,
                                                      XN, in_proj_w, dt_bias, A_log, DTDA);

    ssd_chunk<<<NTAU, 256, 0, stream>>>(Bcb, Ccb, XBC, DTDA, YI, DHb, ESA, DC);
    ssd_carry<<<256, 256, 0, stream>>>(DHb, DC, HPREV);
    ssd_final<<<NTAU, 256, 0, stream>>>(Ccb, ESA, HPREV, XBC, ZX, Dp, YI, PS);

    // fused out_proj + conv2d + BN + ReLU (per-token rms computed in-kernel from PS)
    gemm_bt<1><<<(CIN / 128) * (TOK / 64), 256, 0, stream>>>(WCMB, YI, d_out, CIN, TOK, DIN, 0,
                                                             TOK / 64, BNSC, BNSH, PS);
}

// Round 23
// 138.497 us; speedup vs baseline: 1.0714x; 1.0198x over previous
//
#include <hip/hip_runtime.h>
#include <hip/hip_bf16.h>

// Problem constants
#define NB 8
#define LL 1024        // H*W tokens per batch
#define CIN 512
#define DIN 1024       // d_inner
#define DXBC 1152      // d_inner + 2*d_state
#define DPROJ 2192     // actual in_proj rows
#define NPADW 2304     // ZX row stride (padded)
#define NUSE 2176      // cols of ZX actually consumed (z + xBC); 34 x 64
#define NHH 16
#define HDD 64
#define DST 64
#define NCHUNK 16
#define QCH 64         // chunk length
#define XBCS 1024      // XBC stored stride (x-part only)
#define CTT 8          // conv tokens per block
#define DTB 16         // dt tokens per block
#define NDT (NB * LL / DTB)   // 512 dt blocks (placed FIRST in the fused grid)

typedef unsigned short u16;
typedef unsigned int u32;
typedef __bf16 bf16x8 __attribute__((ext_vector_type(8)));
typedef float f32x4 __attribute__((ext_vector_type(4)));
typedef u16 u16x8 __attribute__((ext_vector_type(8)));

__device__ __forceinline__ float bf2f(u16 u) {
    u32 x = ((u32)u) << 16; float f; __builtin_memcpy(&f, &x, 4); return f;
}
__device__ __forceinline__ u16 f2bf(float f) {
    u32 x; __builtin_memcpy(&x, &f, 4);
    u32 r = x + 0x7fff + ((x >> 16) & 1);
    return (u16)(r >> 16);
}

__device__ __forceinline__ void gload16(const u16* g, u16* l) {
    __builtin_amdgcn_global_load_lds((__attribute__((address_space(1))) void*)(g),
                                     (__attribute__((address_space(3))) void*)(l), 16, 0, 0);
}

// swizzled u16 index into a [64][64] bf16 LDS tile (128B rows, 16B-slot XOR swizzle)
__device__ __forceinline__ int swz(int row, int cb) {
    return row * 64 + ((cb ^ ((row & 7) << 4)) >> 1);
}

// ---------- fused weight prep: Win pad-convert | Wc2 convert | BN prep ----------
#define PREP_WIN_BLKS 4608   // NPADW*CIN/256
#define PREP_WC2_BLKS 1024   // CIN*CIN/256
__global__ __launch_bounds__(256) void prep_all(const float* __restrict__ ipw, u16* __restrict__ Win,
                                                const float* __restrict__ c2w, u16* __restrict__ Wc2,
                                                const float* __restrict__ cb, const float* __restrict__ g,
                                                const float* __restrict__ bb, const float* __restrict__ mean,
                                                const float* __restrict__ var,
                                                float* __restrict__ scale, float* __restrict__ shift) {
    int bid = blockIdx.x;
    if (bid < PREP_WIN_BLKS) {
        int i = bid * 256 + threadIdx.x;
        Win[i] = (i < DPROJ * CIN) ? f2bf(ipw[i]) : (u16)0;
    } else if (bid < PREP_WIN_BLKS + PREP_WC2_BLKS) {
        int i = (bid - PREP_WIN_BLKS) * 256 + threadIdx.x;
        Wc2[i] = f2bf(c2w[i]);
    } else {
        int i = (bid - PREP_WIN_BLKS - PREP_WC2_BLKS) * 256 + threadIdx.x;
        if (i < CIN) {
            float rs = rsqrtf(var[i] + 1e-5f);
            float sc = g[i] * rs;
            scale[i] = sc;
            shift[i] = (cb[i] - mean[i]) * sc + bb[i];
        }
    }
}

// WoutT[d][c] = out_proj_w[c][d] * rms_w[d]   (LDS-tiled transpose, 64x64 tiles)
__global__ __launch_bounds__(256) void woutT_conv(const float* __restrict__ s,
                                                  const float* __restrict__ rw,
                                                  u16* __restrict__ dt) {
    __shared__ float tile[64][65];
    int bc = blockIdx.x & 7, bd = blockIdx.x >> 3;
    int c0 = bc * 64, d0 = bd * 64;
    int t = threadIdx.x;
    int r4 = t >> 6, cc = t & 63;
#pragma unroll
    for (int rr = 0; rr < 16; ++rr) {
        int row = r4 * 16 + rr;
        tile[row][cc] = s[(size_t)(c0 + row) * DIN + d0 + cc];
    }
    __syncthreads();
#pragma unroll
    for (int rr = 0; rr < 16; ++rr) {
        int row = r4 * 16 + rr;
        dt[(size_t)(d0 + row) * CIN + c0 + cc] = f2bf(tile[cc][row] * rw[d0 + row]);
    }
}

// ---------- LayerNorm over channels + transpose (B,C,HW) -> (tok, C) bf16 ----------
// phase 1: thread (hwq = t&7 -> 4 consecutive hw, cg = t>>3 -> 16 channels), float4 loads.
__global__ __launch_bounds__(256) void ln_kernel(const float* __restrict__ x,
                                                 const float* __restrict__ lw,
                                                 const float* __restrict__ lb,
                                                 u16* __restrict__ xn) {
    __shared__ u16 tile[CIN * 33];
    __shared__ float psum[32][32], psq[32][32], muA[32], rsA[32];
    int bid = blockIdx.x;
    int b = bid >> 5, hw0 = (bid & 31) * 32;
    int t = threadIdx.x;
    int hwq = (t & 7) * 4, cg = t >> 3;   // 4 hw positions, 16 channels
    const float* xb = x + (size_t)b * CIN * LL + hw0 + hwq;
    float s0 = 0.f, s1 = 0.f, s2 = 0.f, s3 = 0.f;
    float q0 = 0.f, q1 = 0.f, q2 = 0.f, q3 = 0.f;
#pragma unroll
    for (int k = 0; k < 16; ++k) {
        int c = cg * 16 + k;
        float4 v = *(const float4*)&xb[(size_t)c * LL];
        s0 += v.x; s1 += v.y; s2 += v.z; s3 += v.w;
        q0 += v.x * v.x; q1 += v.y * v.y; q2 += v.z * v.z; q3 += v.w * v.w;
        tile[c * 33 + hwq + 0] = f2bf(v.x);
        tile[c * 33 + hwq + 1] = f2bf(v.y);
        tile[c * 33 + hwq + 2] = f2bf(v.z);
        tile[c * 33 + hwq + 3] = f2bf(v.w);
    }
    psum[cg][hwq + 0] = s0; psq[cg][hwq + 0] = q0;
    psum[cg][hwq + 1] = s1; psq[cg][hwq + 1] = q1;
    psum[cg][hwq + 2] = s2; psq[cg][hwq + 2] = q2;
    psum[cg][hwq + 3] = s3; psq[cg][hwq + 3] = q3;
    __syncthreads();
    if (t < 32) {
        float ss = 0.f, qq = 0.f;
#pragma unroll
        for (int g = 0; g < 32; ++g) { ss += psum[g][t]; qq += psq[g][t]; }
        float mu = ss * (1.f / CIN);
        float var = qq * (1.f / CIN) - mu * mu;
        muA[t] = mu; rsA[t] = rsqrtf(var + 1e-5f);
    }
    __syncthreads();
    for (int r = 0; r < 64; ++r) {
        int idx = r * 256 + t;
        int c = idx & (CIN - 1);
        int hh = idx >> 9;
        float v = (bf2f(tile[c * 33 + hh]) - muA[hh]) * rsA[hh] * lw[c] + lb[c];
        xn[((size_t)(b * LL + hw0 + hh)) * CIN + c] = f2bf(v);
    }
}

// ---------- bf16 MFMA GEMM: 128x64 tile, BK=64, XOR-swizzled LDS, 2-phase counted vmcnt ----------
// EPI 0: bf16 store row-major ldc.
// EPI 1: v*rs(col from PS) -> BN(scale/shift[row]) -> ReLU -> remapped f32 store (d_out layout).
template <int EPI>
__global__ __launch_bounds__(256) void gemm_bt(const u16* __restrict__ A, const u16* __restrict__ Bw,
                                               void* __restrict__ Cout, int M, int N, int K, int ldc,
                                               int nx,
                                               const float* __restrict__ scale,
                                               const float* __restrict__ shift,
                                               const float* __restrict__ PS) {
    __shared__ u16 As[2][128 * 64], Bs[2][64 * 64];
    __shared__ float rsl[64];
    int t = threadIdx.x;
    int lane = t & 63, wave = t >> 6;
    // bijective XCD swizzle (m204)
    int nblk = gridDim.x;
    int qq = nblk >> 3, rm = nblk & 7;
    int xcd = blockIdx.x & 7, idx = blockIdx.x >> 3;
    int swzb = (xcd < rm ? xcd * (qq + 1) : rm * (qq + 1) + (xcd - rm) * qq) + idx;
    int m0 = (swzb / nx) * 128, n0 = (swzb % nx) * 64;
    int wr = wave >> 1, wc = wave & 1;
    f32x4 acc[4][2];
    for (int m = 0; m < 4; ++m)
        for (int n = 0; n < 2; ++n)
            for (int q = 0; q < 4; ++q) acc[m][n][q] = 0.f;

    if (EPI == 1) {
        // per-token rms scale for this block's 64 token-columns
        if (t < 64) {
            int tok = n0 + t;
            int b = tok >> 10, rem = tok & 1023;
            int c = rem >> 6, ii = rem & 63;
            float s = 0.f;
#pragma unroll
            for (int h = 0; h < NHH; ++h)
                s += PS[(size_t)(((b << 4) + h) * 16 + c) * 64 + ii];
            rsl[t] = rsqrtf(s * (1.f / DIN) + 1e-5f);
        }
        __syncthreads();
    }

    const u16* Arow = A + (size_t)m0 * K;
    const u16* Brow = Bw + (size_t)n0 * K;
    int s4 = lane >> 4;
    int rr = lane & 15;

    auto STAGE = [&](int buf, int k0) {
#pragma unroll
        for (int j = 0; j < 4; ++j) {
            int e = j * 256 + t;          // A: 1024 16B-slots, 8 per row
            int r = e >> 3, sr = e & 7;
            int src = (sr ^ (r & 7)) * 8;
            gload16(Arow + (size_t)r * K + k0 + src, &As[buf][e * 8]);
        }
#pragma unroll
        for (int j = 0; j < 2; ++j) {
            int e = j * 256 + t;          // B: 512 16B-slots
            int r = e >> 3, sr = e & 7;
            int src = (sr ^ (r & 7)) * 8;
            gload16(Brow + (size_t)r * K + k0 + src, &Bs[buf][e * 8]);
        }
    };

    STAGE(0, 0);                       // 6 loads/thread in flight
    int NK = K >> 6, cur = 0;
    for (int kt = 0; kt < NK; ++kt) {
        if (kt + 1 < NK) {
            STAGE(cur ^ 1, (kt + 1) << 6);             // +6 loads (next tile)
            asm volatile("s_waitcnt vmcnt(6)" ::: "memory");  // cur tile's 6 done; next 6 fly
        } else {
            asm volatile("s_waitcnt vmcnt(0)" ::: "memory");
        }
        __builtin_amdgcn_s_barrier();   // all waves' cur-tile loads landed
        __builtin_amdgcn_sched_barrier(0);
#pragma unroll
        for (int kk = 0; kk < 2; ++kk) {
            bf16x8 af[4], bfr[2];
#pragma unroll
            for (int m = 0; m < 4; ++m) {
                int row = wr * 64 + m * 16 + rr;
                int ss = (kk * 4 + s4) ^ (row & 7);
                af[m] = *(const bf16x8*)&As[cur][row * 64 + ss * 8];
            }
#pragma unroll
            for (int n = 0; n < 2; ++n) {
                int row = wc * 32 + n * 16 + rr;
                int ss = (kk * 4 + s4) ^ (row & 7);
                bfr[n] = *(const bf16x8*)&Bs[cur][row * 64 + ss * 8];
            }
#pragma unroll
            for (int m = 0; m < 4; ++m)
#pragma unroll
                for (int n = 0; n < 2; ++n)
                    acc[m][n] = __builtin_amdgcn_mfma_f32_16x16x32_bf16(af[m], bfr[n], acc[m][n], 0, 0, 0);
        }
        __builtin_amdgcn_s_barrier();   // protect buf[cur] before next iter's STAGE overwrites it
        cur ^= 1;
    }
    int fq = lane >> 4, fr = lane & 15;
#pragma unroll
    for (int m = 0; m < 4; ++m) {
#pragma unroll
        for (int n = 0; n < 2; ++n) {
            int col = n0 + wc * 32 + n * 16 + fr;
#pragma unroll
            for (int q = 0; q < 4; ++q) {
                int row = m0 + wr * 64 + m * 16 + fq * 4 + q;
                float v = acc[m][n][q];
                if (EPI == 0) {
                    ((u16*)Cout)[(size_t)row * ldc + col] = f2bf(v);
                } else {
                    v = v * rsl[col - n0];
                    v = v * scale[row] + shift[row];
                    v = v > 0.f ? v : 0.f;
                    // row = out-channel o, col = token (b*1024+hw)
                    ((float*)Cout)[((size_t)(col >> 10)) * (CIN * LL) + (size_t)row * LL + (col & 1023)] = v;
                }
            }
        }
    }
}

// ---------- fused: dt GEMV (blocks 0..511) | depthwise conv1d+SiLU (blocks 512..1535) ----------
__global__ __launch_bounds__(288) void convdt(const u16* __restrict__ zx,
                                              const float* __restrict__ w,
                                              const float* __restrict__ bias,
                                              u16* __restrict__ xbc,
                                              u16* __restrict__ Bc, u16* __restrict__ Cc,
                                              const u16* __restrict__ xn,
                                              const float* __restrict__ wproj,
                                              const float* __restrict__ dt_bias,
                                              const float* __restrict__ A_log,
                                              float2* __restrict__ dtda) {
    int bid = blockIdx.x;
    int t = threadIdx.x;
    if (bid >= NDT) {
        // ---- conv branch ----
        int cb = bid - NDT;
        int b = cb >> 7;
        int l0 = (cb & 127) * CTT;
        bool isX = t < 256;
        int ch = isX ? t * 4 : 1024 + (t - 256) * 4;

        float4 wv0 = *(const float4*)&w[(ch + 0) * 4];
        float4 wv1 = *(const float4*)&w[(ch + 1) * 4];
        float4 wv2 = *(const float4*)&w[(ch + 2) * 4];
        float4 wv3 = *(const float4*)&w[(ch + 3) * 4];
        float4 bv = *(const float4*)&bias[ch];

        ushort4 xin[CTT + 3];
        const u16* src = zx + (size_t)(b * LL + l0 - 3) * NPADW + DIN + ch;
#pragma unroll
        for (int i = 0; i < CTT + 3; ++i) {
            ushort4 v = {0, 0, 0, 0};
            if (l0 + i - 3 >= 0) v = *(const ushort4*)(src + (size_t)i * NPADW);
            xin[i] = v;
        }
#pragma unroll
        for (int i = 0; i < CTT; ++i) {
            int tok = b * LL + l0 + i;
            float a0 = bv.x + bf2f(xin[i].x) * wv0.x + bf2f(xin[i + 1].x) * wv0.y +
                       bf2f(xin[i + 2].x) * wv0.z + bf2f(xin[i + 3].x) * wv0.w;
            float a1 = bv.y + bf2f(xin[i].y) * wv1.x + bf2f(xin[i + 1].y) * wv1.y +
                       bf2f(xin[i + 2].y) * wv1.z + bf2f(xin[i + 3].y) * wv1.w;
            float a2 = bv.z + bf2f(xin[i].z) * wv2.x + bf2f(xin[i + 1].z) * wv2.y +
                       bf2f(xin[i + 2].z) * wv2.z + bf2f(xin[i + 3].z) * wv2.w;
            float a3 = bv.w + bf2f(xin[i].w) * wv3.x + bf2f(xin[i + 1].w) * wv3.y +
                       bf2f(xin[i + 2].w) * wv3.z + bf2f(xin[i + 3].w) * wv3.w;
            float s0 = a0 / (1.f + __expf(-a0));
            float s1 = a1 / (1.f + __expf(-a1));
            float s2 = a2 / (1.f + __expf(-a2));
            float s3 = a3 / (1.f + __expf(-a3));
            ushort4 o;
            o.x = f2bf(s0); o.y = f2bf(s1); o.z = f2bf(s2); o.w = f2bf(s3);
            if (isX) {
                *(ushort4*)&xbc[(size_t)tok * XBCS + ch] = o;
            } else {
                int s = ch - 1024;
                if (s < DST) *(ushort4*)&Bc[(size_t)tok * DST + s] = o;
                else         *(ushort4*)&Cc[(size_t)tok * DST + (s - DST)] = o;
            }
        }
    } else {
        // ---- dt branch (256 active threads) ----
        if (t >= 256) return;
        int h = t >> 4, part = t & 15;
        int tok0 = bid * DTB;
        const float* wr = wproj + (size_t)(DIN + DXBC + h) * CIN + part * 32;
        float4 wv[8];
#pragma unroll
        for (int i = 0; i < 8; ++i) wv[i] = *(const float4*)&wr[i * 4];
        const float* wf = (const float*)wv;
        float dtb = dt_bias[h];
        float An = -__expf(A_log[h]);
#pragma unroll
        for (int tl = 0; tl < DTB; ++tl) {
            int tok = tok0 + tl;
            const u16* xr = xn + (size_t)tok * CIN + part * 32;
            u16x8 xv0 = *(const u16x8*)&xr[0];
            u16x8 xv1 = *(const u16x8*)&xr[8];
            u16x8 xv2 = *(const u16x8*)&xr[16];
            u16x8 xv3 = *(const u16x8*)&xr[24];
            float s = 0.f;
#pragma unroll
            for (int i = 0; i < 8; ++i) s += bf2f(xv0[i]) * wf[i];
#pragma unroll
            for (int i = 0; i < 8; ++i) s += bf2f(xv1[i]) * wf[8 + i];
#pragma unroll
            for (int i = 0; i < 8; ++i) s += bf2f(xv2[i]) * wf[16 + i];
#pragma unroll
            for (int i = 0; i < 8; ++i) s += bf2f(xv3[i]) * wf[24 + i];
            s += __shfl_xor(s, 1, 64);
            s += __shfl_xor(s, 2, 64);
            s += __shfl_xor(s, 4, 64);
            s += __shfl_xor(s, 8, 64);
            if (part == 0) {
                float si = s + dtb;
                float dtv = si > 15.f ? si : __logf(1.f + __expf(si));
                float2 dd; dd.x = dtv; dd.y = dtv * An;
                dtda[(size_t)tok * NHH + h] = dd;
            }
        }
    }
}

// ---------- SSD K1: G̃, Y_intra(bf16), ΔH(bf16), ESA, d_c ----------
__global__ __launch_bounds__(256) void ssd_chunk(const u16* __restrict__ Bcb,
                                                 const u16* __restrict__ Ccb,
                                                 const u16* __restrict__ xbc,
                                                 const float2* __restrict__ dtda,
                                                 u16* __restrict__ yi,
                                                 u16* __restrict__ DHb,
                                                 float* __restrict__ ESA,
                                                 float* __restrict__ DC) {
    __shared__ u16 Bt[4096], Ct[4096], XT[4096], BTt[4096], Gt[4096];
    __shared__ float Sar[64], dtvA[64], wA[64];
    int tau = blockIdx.x;
    int b = tau >> 8, h = (tau >> 4) & 15, c = tau & 15;
    int t0g = b * LL + c * QCH;
    int t = threadIdx.x, lane = t & 63, wave = t >> 6;
    int row = t >> 2, q = t & 3;

    {
        const u16* bp = Bcb + (size_t)(t0g + row) * DST + q * 16;
        const u16* cp = Ccb + (size_t)(t0g + row) * DST + q * 16;
        u16x8 b0v = *(const u16x8*)bp;
        u16x8 b1v = *(const u16x8*)(bp + 8);
        *(u16x8*)&Bt[swz(row, q * 32)] = b0v;
        *(u16x8*)&Bt[swz(row, q * 32 + 16)] = b1v;
        u16x8 c0v = *(const u16x8*)cp;
        u16x8 c1v = *(const u16x8*)(cp + 8);
        *(u16x8*)&Ct[swz(row, q * 32)] = c0v;
        *(u16x8*)&Ct[swz(row, q * 32 + 16)] = c1v;
        const u16* xp = xbc + (size_t)(t0g + row) * XBCS + h * HDD + q * 16;
        u16x8 x0 = *(const u16x8*)xp;
        u16x8 x1 = *(const u16x8*)(xp + 8);
#pragma unroll
        for (int e = 0; e < 8; ++e) XT[swz(q * 16 + e, row * 2)] = x0[e];
#pragma unroll
        for (int e = 0; e < 8; ++e) XT[swz(q * 16 + 8 + e, row * 2)] = x1[e];
    }
    if (t < 64) {
        float2 dd = dtda[(size_t)(t0g + t) * NHH + h];
        float s = dd.y;
#pragma unroll
        for (int off = 1; off < 64; off <<= 1) {
            float u = __shfl_up(s, off, 64);
            if (t >= off) s += u;
        }
        float SQ = __shfl(s, 63, 64);
        Sar[t] = s; dtvA[t] = dd.x;
        wA[t] = __expf(SQ - s) * dd.x;
        ESA[(size_t)tau * 64 + t] = __expf(s);
        if (t == 0) DC[tau] = __expf(SQ);
    }
    __syncthreads();

    int R = wave >> 1, Cq = wave & 1, rr = lane & 15, sg = lane >> 4;
    f32x4 g[2][2];
#pragma unroll
    for (int mi = 0; mi < 2; ++mi)
#pragma unroll
        for (int ni = 0; ni < 2; ++ni)
#pragma unroll
            for (int r = 0; r < 4; ++r) g[mi][ni][r] = 0.f;
#pragma unroll
    for (int kt = 0; kt < 2; ++kt) {
        int cb = kt * 64 + sg * 16;
        bf16x8 a0 = *(const bf16x8*)&Ct[swz(R * 32 + rr, cb)];
        bf16x8 a1 = *(const bf16x8*)&Ct[swz(R * 32 + 16 + rr, cb)];
        bf16x8 b0 = *(const bf16x8*)&Bt[swz(Cq * 32 + rr, cb)];
        bf16x8 b1 = *(const bf16x8*)&Bt[swz(Cq * 32 + 16 + rr, cb)];
        g[0][0] = __builtin_amdgcn_mfma_f32_16x16x32_bf16(a0, b0, g[0][0], 0, 0, 0);
        g[0][1] = __builtin_amdgcn_mfma_f32_16x16x32_bf16(a0, b1, g[0][1], 0, 0, 0);
        g[1][0] = __builtin_amdgcn_mfma_f32_16x16x32_bf16(a1, b0, g[1][0], 0, 0, 0);
        g[1][1] = __builtin_amdgcn_mfma_f32_16x16x32_bf16(a1, b1, g[1][1], 0, 0, 0);
    }
#pragma unroll
    for (int mi = 0; mi < 2; ++mi)
#pragma unroll
        for (int ni = 0; ni < 2; ++ni)
#pragma unroll
            for (int r = 0; r < 4; ++r) {
                int i = R * 32 + mi * 16 + sg * 4 + r;
                int j = Cq * 32 + ni * 16 + rr;
                float v = (i >= j) ? g[mi][ni][r] * __expf(Sar[i] - Sar[j]) * dtvA[j] : 0.f;
                Gt[swz(i, j * 2)] = f2bf(v);
            }
    // B~T (LDS, transposed, scaled by wA)
#pragma unroll
    for (int half = 0; half < 2; ++half) {
        u16x8 bv = *(const u16x8*)&Bt[swz(row, q * 32 + half * 16)];
#pragma unroll
        for (int e = 0; e < 8; ++e)
            BTt[swz(q * 16 + half * 8 + e, row * 2)] = f2bf(bf2f(bv[e]) * wA[row]);
    }
    __syncthreads();

    f32x4 y[2][2], dh[2][2];
#pragma unroll
    for (int mi = 0; mi < 2; ++mi)
#pragma unroll
        for (int ni = 0; ni < 2; ++ni)
#pragma unroll
            for (int r = 0; r < 4; ++r) { y[mi][ni][r] = 0.f; dh[mi][ni][r] = 0.f; }
#pragma unroll
    for (int kt = 0; kt < 2; ++kt) {
        int cb = kt * 64 + sg * 16;
        bf16x8 xb0 = *(const bf16x8*)&XT[swz(Cq * 32 + rr, cb)];
        bf16x8 xb1 = *(const bf16x8*)&XT[swz(Cq * 32 + 16 + rr, cb)];
        bf16x8 ga0 = *(const bf16x8*)&Gt[swz(R * 32 + rr, cb)];
        bf16x8 ga1 = *(const bf16x8*)&Gt[swz(R * 32 + 16 + rr, cb)];
        bf16x8 ba0 = *(const bf16x8*)&BTt[swz(R * 32 + rr, cb)];
        bf16x8 ba1 = *(const bf16x8*)&BTt[swz(R * 32 + 16 + rr, cb)];
        y[0][0] = __builtin_amdgcn_mfma_f32_16x16x32_bf16(ga0, xb0, y[0][0], 0, 0, 0);
        y[0][1] = __builtin_amdgcn_mfma_f32_16x16x32_bf16(ga0, xb1, y[0][1], 0, 0, 0);
        y[1][0] = __builtin_amdgcn_mfma_f32_16x16x32_bf16(ga1, xb0, y[1][0], 0, 0, 0);
        y[1][1] = __builtin_amdgcn_mfma_f32_16x16x32_bf16(ga1, xb1, y[1][1], 0, 0, 0);
        dh[0][0] = __builtin_amdgcn_mfma_f32_16x16x32_bf16(ba0, xb0, dh[0][0], 0, 0, 0);
        dh[0][1] = __builtin_amdgcn_mfma_f32_16x16x32_bf16(ba0, xb1, dh[0][1], 0, 0, 0);
        dh[1][0] = __builtin_amdgcn_mfma_f32_16x16x32_bf16(ba1, xb0, dh[1][0], 0, 0, 0);
        dh[1][1] = __builtin_amdgcn_mfma_f32_16x16x32_bf16(ba1, xb1, dh[1][1], 0, 0, 0);
    }
#pragma unroll
    for (int mi = 0; mi < 2; ++mi)
#pragma unroll
        for (int ni = 0; ni < 2; ++ni)
#pragma unroll
            for (int r = 0; r < 4; ++r) {
                int i = R * 32 + mi * 16 + sg * 4 + r;
                int p = Cq * 32 + ni * 16 + rr;
                yi[(size_t)(t0g + i) * DIN + h * HDD + p] = f2bf(y[mi][ni][r]);
                DHb[(size_t)tau * 4096 + i * 64 + p] = f2bf(dh[mi][ni][r]);
            }
}

// ---------- SSD K2: sequential chunk-state carry ----------
__global__ __launch_bounds__(256) void ssd_carry(const u16* __restrict__ DHb,
                                                 const float* __restrict__ DC,
                                                 u16* __restrict__ HPREV) {
    int bid = blockIdx.x;
    int bh = bid >> 1, ph = bid & 1;
    int t = threadIdx.x;
    int s = t >> 2, p0 = ph * 32 + (t & 3) * 8;
    size_t base = (size_t)bh * NCHUNK * 4096 + s * 64 + p0;
    float Hv[8] = {0.f, 0.f, 0.f, 0.f, 0.f, 0.f, 0.f, 0.f};
    for (int c = 0; c < NCHUNK; ++c) {
        size_t off = base + (size_t)c * 4096;
        u16x8 hp;
#pragma unroll
        for (int e = 0; e < 8; ++e) hp[e] = f2bf(Hv[e]);
        *(u16x8*)&HPREV[off] = hp;
        float d = DC[bh * NCHUNK + c];
        u16x8 dv = *(const u16x8*)&DHb[off];
#pragma unroll
        for (int e = 0; e < 8; ++e) Hv[e] = d * Hv[e] + bf2f(dv[e]);
    }
}

// ---------- SSD K3: Y = Y_intra + (C·eS)·Hprev; fuse D·x, z-gate; emit per-tau y² partials ----------
__global__ __launch_bounds__(256) void ssd_final(const u16* __restrict__ Ccb,
                                                 const float* __restrict__ ESA,
                                                 const u16* __restrict__ HPREV,
                                                 const u16* __restrict__ xbc,
                                                 const u16* __restrict__ zx,
                                                 const float* __restrict__ Dp,
                                                 u16* __restrict__ yi,
                                                 float* __restrict__ PS) {
    __shared__ u16 C2t[4096], HT[4096];
    __shared__ float smem_ps[2][64];
    int tau = blockIdx.x;
    int b = tau >> 8, h = (tau >> 4) & 15, c = tau & 15;
    int t0g = b * LL + c * QCH;
    int t = threadIdx.x, lane = t & 63, wave = t >> 6;
    int row = t >> 2, q = t & 3;
    {
        float esa = ESA[(size_t)tau * 64 + row];
        const u16* cp = Ccb + (size_t)(t0g + row) * DST + q * 16;
#pragma unroll
        for (int half = 0; half < 2; ++half) {
            u16x8 cv = *(const u16x8*)(cp + half * 8);
            u16x8 oc;
#pragma unroll
            for (int e = 0; e < 8; ++e) oc[e] = f2bf(bf2f(cv[e]) * esa);
            *(u16x8*)&C2t[swz(row, q * 32 + half * 16)] = oc;
            u16x8 hv = *(const u16x8*)&HPREV[(size_t)tau * 4096 + row * 64 + q * 16 + half * 8];
#pragma unroll
            for (int e = 0; e < 8; ++e) HT[swz(q * 16 + half * 8 + e, row * 2)] = hv[e];
        }
    }
    __syncthreads();
    int R = wave >> 1, Cq = wave & 1, rr = lane & 15, sg = lane >> 4;
    float Dh = Dp[h];
    f32x4 acc[2][2];
#pragma unroll
    for (int mi = 0; mi < 2; ++mi)
#pragma unroll
        for (int ni = 0; ni < 2; ++ni)
#pragma unroll
            for (int r = 0; r < 4; ++r) {
                int i = R * 32 + mi * 16 + sg * 4 + r;
                int p = Cq * 32 + ni * 16 + rr;
                acc[mi][ni][r] = bf2f(yi[(size_t)(t0g + i) * DIN + h * HDD + p]);
            }
#pragma unroll
    for (int kt = 0; kt < 2; ++kt) {
        int cb = kt * 64 + sg * 16;
        bf16x8 a0 = *(const bf16x8*)&C2t[swz(R * 32 + rr, cb)];
        bf16x8 a1 = *(const bf16x8*)&C2t[swz(R * 32 + 16 + rr, cb)];
        bf16x8 b0 = *(const bf16x8*)&HT[swz(Cq * 32 + rr, cb)];
        bf16x8 b1 = *(const bf16x8*)&HT[swz(Cq * 32 + 16 + rr, cb)];
        acc[0][0] = __builtin_amdgcn_mfma_f32_16x16x32_bf16(a0, b0, acc[0][0], 0, 0, 0);
        acc[0][1] = __builtin_amdgcn_mfma_f32_16x16x32_bf16(a0, b1, acc[0][1], 0, 0, 0);
        acc[1][0] = __builtin_amdgcn_mfma_f32_16x16x32_bf16(a1, b0, acc[1][0], 0, 0, 0);
        acc[1][1] = __builtin_amdgcn_mfma_f32_16x16x32_bf16(a1, b1, acc[1][1], 0, 0, 0);
    }
    float ps[2][4];
#pragma unroll
    for (int mi = 0; mi < 2; ++mi)
#pragma unroll
        for (int r = 0; r < 4; ++r) ps[mi][r] = 0.f;
#pragma unroll
    for (int mi = 0; mi < 2; ++mi)
#pragma unroll
        for (int ni = 0; ni < 2; ++ni)
#pragma unroll
            for (int r = 0; r < 4; ++r) {
                int i = R * 32 + mi * 16 + sg * 4 + r;
                int p = Cq * 32 + ni * 16 + rr;
                size_t tok = t0g + i;
                int col = h * HDD + p;
                float xf = bf2f(xbc[tok * XBCS + col]);
                float zf = bf2f(zx[tok * NPADW + col]);
                float yo = (acc[mi][ni][r] + Dh * xf) * (zf / (1.f + __expf(-zf)));
                yi[tok * DIN + col] = f2bf(yo);
                ps[mi][r] += yo * yo;
            }
#pragma unroll
    for (int mi = 0; mi < 2; ++mi)
#pragma unroll
        for (int r = 0; r < 4; ++r) {
            float s2 = ps[mi][r];
            s2 += __shfl_xor(s2, 1, 64);
            s2 += __shfl_xor(s2, 2, 64);
            s2 += __shfl_xor(s2, 4, 64);
            s2 += __shfl_xor(s2, 8, 64);
            if (rr == 0) smem_ps[Cq][R * 32 + mi * 16 + sg * 4 + r] = s2;
        }
    __syncthreads();
    if (t < 64) PS[(size_t)tau * 64 + t] = smem_ps[0][t] + smem_ps[1][t];
}

extern "C" void kernel_launch(void* const* d_in, const int* in_sizes, int n_in,
                              void* d_out, int out_size, void* d_ws, size_t ws_size,
                              hipStream_t stream) {
    const float* x         = (const float*)d_in[0];
    const float* ln_w      = (const float*)d_in[1];
    const float* ln_b      = (const float*)d_in[2];
    const float* in_proj_w = (const float*)d_in[3];
    const float* conv1d_w  = (const float*)d_in[4];
    const float* conv1d_b  = (const float*)d_in[5];
    const float* dt_bias   = (const float*)d_in[6];
    const float* A_log     = (const float*)d_in[7];
    const float* Dp        = (const float*)d_in[8];
    const float* rms_w     = (const float*)d_in[9];
    const float* out_proj_w= (const float*)d_in[10];
    const float* conv2d_w  = (const float*)d_in[11];
    const float* conv2d_b  = (const float*)d_in[12];
    const float* bn_g      = (const float*)d_in[13];
    const float* bn_b      = (const float*)d_in[14];
    const float* bn_mean   = (const float*)d_in[15];
    const float* bn_var    = (const float*)d_in[16];

    const int TOK = NB * LL;  // 8192
    const int NTAU = NB * NHH * NCHUNK;  // 2048
    char* ws = (char*)d_ws;
    size_t off = 0;
    auto alloc = [&](size_t bytes) {
        void* p = ws + off;
        off += (bytes + 255) & ~(size_t)255;
        return p;
    };
    u16*   Win   = (u16*)alloc((size_t)NPADW * CIN * 2);
    u16*   WoutT = (u16*)alloc((size_t)DIN * CIN * 2);
    u16*   Wc2   = (u16*)alloc((size_t)CIN * CIN * 2);
    u16*   WCMB  = (u16*)alloc((size_t)CIN * DIN * 2);
    u16*   XN    = (u16*)alloc((size_t)TOK * CIN * 2);
    u16*   ZX    = (u16*)alloc((size_t)TOK * NPADW * 2);
    u16*   XBC   = (u16*)alloc((size_t)TOK * XBCS * 2);
    u16*   Bcb   = (u16*)alloc((size_t)TOK * DST * 2);
    u16*   Ccb   = (u16*)alloc((size_t)TOK * DST * 2);
    float2* DTDA = (float2*)alloc((size_t)TOK * NHH * 8);
    u16*   YI    = (u16*)alloc((size_t)TOK * DIN * 2);
    u16*   DHb   = (u16*)alloc((size_t)NTAU * 4096 * 2);
    u16*   HPREV = (u16*)alloc((size_t)NTAU * 4096 * 2);
    float* ESA   = (float*)alloc((size_t)NTAU * 64 * 4);
    float* PS    = (float*)alloc((size_t)NTAU * 64 * 4);
    float* DC    = (float*)alloc((size_t)NTAU * 4);
    float* BNSC  = (float*)alloc(CIN * 4);
    float* BNSH  = (float*)alloc(CIN * 4);

    // fused weight prep
    prep_all<<<PREP_WIN_BLKS + PREP_WC2_BLKS + 2, 256, 0, stream>>>(
        in_proj_w, Win, conv2d_w, Wc2, conv2d_b, bn_g, bn_b, bn_mean, bn_var, BNSC, BNSH);
    woutT_conv<<<128, 256, 0, stream>>>(out_proj_w, rms_w, WoutT);
    // W_comb[o][d] = sum_c Wc2[o][c] * WoutT[d][c]   (M=512, N=1024, K=512)
    gemm_bt<0><<<(CIN / 128) * (DIN / 64), 256, 0, stream>>>(Wc2, WoutT, WCMB, CIN, DIN, CIN, DIN,
                                                             DIN / 64, nullptr, nullptr, nullptr);

    ln_kernel<<<256, 256, 0, stream>>>(x, ln_w, ln_b, XN);

    // in_proj: only the NUSE=2176 consumed columns (z + xBC)
    gemm_bt<0><<<(TOK / 128) * (NUSE / 64), 256, 0, stream>>>(XN, Win, ZX, TOK, NUSE, CIN, NPADW,
                                                              NUSE / 64, nullptr, nullptr, nullptr);

    // fused dt (first) + conv1d
    convdt<<<NDT + NB * (LL / CTT), 288, 0, stream>>>(ZX, conv1d_w, conv1d_b, XBC, Bcb, Ccb,
                                                      XN, in_proj_w, dt_bias, A_log, DTDA);

    ssd_chunk<<<NTAU, 256, 0, stream>>>(Bcb, Ccb, XBC, DTDA, YI, DHb, ESA, DC);
    ssd_carry<<<256, 256, 0, stream>>>(DHb, DC, HPREV);
    ssd_final<<<NTAU, 256, 0, stream>>>(Ccb, ESA, HPREV, XBC, ZX, Dp, YI, PS);

    // fused out_proj + conv2d + BN + ReLU (per-token rms computed in-kernel from PS)
    gemm_bt<1><<<(CIN / 128) * (TOK / 64), 256, 0, stream>>>(WCMB, YI, d_out, CIN, TOK, DIN, 0,
                                                             TOK / 64, BNSC, BNSH, PS);
}